// Round 17
// baseline (249.740 us; speedup 1.0000x reference)
//
#include <hip/hip_runtime.h>
#include <hip/hip_bf16.h>
#include <math.h>

#define TT 512
#define CC 768
#define HH 12
#define DD 64
#define KKEEP 64
#define TOPG 128
#define NTCE (TT * CC)
#define NPAIR 36
#define PW (5 * CC)  // hoa plane width

typedef __attribute__((ext_vector_type(8))) short bf16x8;
typedef __attribute__((ext_vector_type(8))) unsigned short ushort8v;
typedef __attribute__((ext_vector_type(4))) float f32x4;
typedef unsigned long long u64;

// ---------------- helpers ----------------
__device__ __forceinline__ float block_sum(float v, float* red) {
#pragma unroll
  for (int off = 32; off; off >>= 1) v += __shfl_xor(v, off);
  __syncthreads();
  if ((threadIdx.x & 63) == 0) red[threadIdx.x >> 6] = v;
  __syncthreads();
  return red[0] + red[1] + red[2] + red[3];
}

__device__ __forceinline__ unsigned short f32_to_bf16_rne(float f) {
  unsigned u = __float_as_uint(f);
  unsigned r = (u + 0x7FFFu + ((u >> 16) & 1u)) >> 16;
  return (unsigned short)r;
}
__device__ __forceinline__ float bf16_to_f32(unsigned short h) {
  return __uint_as_float(((unsigned)h) << 16);
}
__device__ __forceinline__ void split2(float x, unsigned short& h, unsigned short& l) {
  h = f32_to_bf16_rne(x);
  l = f32_to_bf16_rne(x - bf16_to_f32(h));
}
__device__ __forceinline__ int swz(int row, int k) {
  return row * 64 + ((((k >> 3) ^ (row & 7))) << 3) + (k & 7);
}

// ---------------- weight split+transpose (all 10 weights, one dispatch) ----------------
struct WSplitArgs {
  const float* src[10];
  unsigned short* hi[10];
  unsigned short* lo[10];
  int K[10], N[10], tstart[10];
};

__global__ __launch_bounds__(256) void wsplitT_kernel(WSplitArgs a) {
  __shared__ float tile_[64][65];
  int t = blockIdx.x;
  int wsel = 0;
#pragma unroll
  for (int i = 1; i < 10; i++)
    if (t >= a.tstart[i]) wsel = i;
  int local = t - a.tstart[wsel];
  int K = a.K[wsel], N = a.N[wsel];
  int ntn = N >> 6;
  int bn = local % ntn, bk = local / ntn;
  int tid = threadIdx.x, r = tid >> 2, cq = tid & 3;
  const float* src = a.src[wsel] + (size_t)(bk * 64 + r) * N + bn * 64 + cq * 16;
#pragma unroll
  for (int f = 0; f < 4; f++) {
    float4 v = *(const float4*)(src + f * 4);
    tile_[r][cq * 16 + f * 4 + 0] = v.x;
    tile_[r][cq * 16 + f * 4 + 1] = v.y;
    tile_[r][cq * 16 + f * 4 + 2] = v.z;
    tile_[r][cq * 16 + f * 4 + 3] = v.w;
  }
  __syncthreads();
  size_t dst = (size_t)(bn * 64 + r) * K + bk * 64 + cq * 16;
  unsigned short hv[16], lv[16];
#pragma unroll
  for (int i = 0; i < 16; i++) split2(tile_[cq * 16 + i][r], hv[i], lv[i]);
  *(ushort8v*)&a.hi[wsel][dst] = *(const ushort8v*)&hv[0];
  *(ushort8v*)&a.hi[wsel][dst + 8] = *(const ushort8v*)&hv[8];
  *(ushort8v*)&a.lo[wsel][dst] = *(const ushort8v*)&lv[0];
  *(ushort8v*)&a.lo[wsel][dst + 8] = *(const ushort8v*)&lv[8];
}

// ---------------- layernorm (planes out; optional fused gate-score dot) ----------------
__global__ void ln_bf_kernel(const float* __restrict__ x, const float* __restrict__ w,
                             const float* __restrict__ b,
                             unsigned short* __restrict__ ohi, unsigned short* __restrict__ olo,
                             const float* __restrict__ gw, const float* __restrict__ gb,
                             float* __restrict__ gscore) {
  int t = blockIdx.x, tid = threadIdx.x;
  __shared__ float red[4];
  float ls = 0.f;
  for (int c = tid; c < CC; c += 256) ls += x[t * CC + c];
  float mean = block_sum(ls, red) * (1.f / CC);
  float lv = 0.f;
  for (int c = tid; c < CC; c += 256) { float d = x[t * CC + c] - mean; lv += d * d; }
  float var = block_sum(lv, red) * (1.f / CC);
  float rs = rsqrtf(var + 1e-5f);
  float gpart = 0.f;
  for (int c = tid; c < CC; c += 256) {
    float val = (x[t * CC + c] - mean) * rs * w[c] + b[c];
    if (gscore) gpart += val * gw[c];
    unsigned short hb, lb;
    split2(val, hb, lb);
    ohi[t * CC + c] = hb;
    olo[t * CC + c] = lb;
  }
  if (gscore) {
    float s = block_sum(gpart, red);
    if (tid == 0) gscore[t] = s + gb[0];
  }
}

// ---------------- split-bf16 MFMA GEMM (passes=3 exact, passes=1 fast bf16) ----------
__global__ __launch_bounds__(256) void gemm_bf(
    const unsigned short* __restrict__ Ah, const unsigned short* __restrict__ Al,
    const unsigned short* __restrict__ Bh, const unsigned short* __restrict__ Bl,
    const float* __restrict__ bias, float* __restrict__ Cf,
    unsigned short* __restrict__ Chi, unsigned short* __restrict__ Clo,
    int M, int N, int K, int act, int seg, const float* __restrict__ res,
    const float* __restrict__ rowmask, float* __restrict__ part, int passes) {
  __shared__ unsigned short AsH[64 * 64], AsL[64 * 64], BsH[64 * 64], BsL[64 * 64];
  int tid = threadIdx.x, lane = tid & 63, wave = tid >> 6;
  int wr = wave >> 1, wc = wave & 1, lr = lane & 15;
  int ksub = (lane >> 4) * 8;
  int n0 = blockIdx.x * 64, m0 = blockIdx.y * 64;
  int lrow = tid >> 2, lq = tid & 3;
  int kchunk = K / gridDim.z;
  int kstart = blockIdx.z * kchunk;

  f32x4 acc[2][2];
#pragma unroll
  for (int i = 0; i < 2; i++)
#pragma unroll
    for (int j = 0; j < 2; j++) acc[i][j] = (f32x4){0.f, 0.f, 0.f, 0.f};

  for (int k0 = kstart; k0 < kstart + kchunk; k0 += 64) {
    size_t aoff = (size_t)(m0 + lrow) * K + k0 + lq * 16;
    size_t boff = (size_t)(n0 + lrow) * K + k0 + lq * 16;
    int d0 = lrow * 64 + (((lq * 2) ^ (lrow & 7)) << 3);
    int d1 = lrow * 64 + (((lq * 2 + 1) ^ (lrow & 7)) << 3);
    *(ushort8v*)&AsH[d0] = *(const ushort8v*)&Ah[aoff];
    *(ushort8v*)&AsH[d1] = *(const ushort8v*)&Ah[aoff + 8];
    *(ushort8v*)&BsH[d0] = *(const ushort8v*)&Bh[boff];
    *(ushort8v*)&BsH[d1] = *(const ushort8v*)&Bh[boff + 8];
    if (passes == 3) {
      *(ushort8v*)&AsL[d0] = *(const ushort8v*)&Al[aoff];
      *(ushort8v*)&AsL[d1] = *(const ushort8v*)&Al[aoff + 8];
      *(ushort8v*)&BsL[d0] = *(const ushort8v*)&Bl[boff];
      *(ushort8v*)&BsL[d1] = *(const ushort8v*)&Bl[boff + 8];
    }
    __syncthreads();
#pragma unroll
    for (int kb = 0; kb < 2; kb++) {
      int kloc = kb * 32 + ksub;
      bf16x8 ah[2], al[2], bh[2], bl[2];
#pragma unroll
      for (int i = 0; i < 2; i++) {
        int m = wr * 32 + i * 16 + lr;
        int off = swz(m, kloc);
        ah[i] = *(const bf16x8*)&AsH[off];
        if (passes == 3) al[i] = *(const bf16x8*)&AsL[off];
      }
#pragma unroll
      for (int j = 0; j < 2; j++) {
        int n = wc * 32 + j * 16 + lr;
        int off = swz(n, kloc);
        bh[j] = *(const bf16x8*)&BsH[off];
        if (passes == 3) bl[j] = *(const bf16x8*)&BsL[off];
      }
#pragma unroll
      for (int i = 0; i < 2; i++)
#pragma unroll
        for (int j = 0; j < 2; j++) {
          acc[i][j] = __builtin_amdgcn_mfma_f32_16x16x32_bf16(ah[i], bh[j], acc[i][j], 0, 0, 0);
          if (passes == 3) {
            acc[i][j] = __builtin_amdgcn_mfma_f32_16x16x32_bf16(ah[i], bl[j], acc[i][j], 0, 0, 0);
            acc[i][j] = __builtin_amdgcn_mfma_f32_16x16x32_bf16(al[i], bh[j], acc[i][j], 0, 0, 0);
          }
        }
    }
    __syncthreads();
  }
  if (part) {
    float* pb = part + (size_t)blockIdx.z * M * N;
#pragma unroll
    for (int i = 0; i < 2; i++)
#pragma unroll
      for (int j = 0; j < 2; j++) {
        int col = n0 + wc * 32 + j * 16 + lr;
#pragma unroll
        for (int q = 0; q < 4; q++) {
          int row = m0 + wr * 32 + i * 16 + (lane >> 4) * 4 + q;
          pb[(size_t)row * N + col] = acc[i][j][q];
        }
      }
    return;
  }
#pragma unroll
  for (int i = 0; i < 2; i++)
#pragma unroll
    for (int j = 0; j < 2; j++) {
      int col = n0 + wc * 32 + j * 16 + lr;
      float bv = bias ? bias[col] : 0.f;
#pragma unroll
      for (int q = 0; q < 4; q++) {
        int row = m0 + wr * 32 + i * 16 + (lane >> 4) * 4 + q;
        float v = acc[i][j][q] + bv;
        if (act == 1) v = 0.5f * v * (1.f + erff(v * 0.70710678118654752f));
        if (rowmask) v *= rowmask[row];
        if (Cf) {
          size_t off = seg ? (size_t)(col / CC) * NTCE + (size_t)row * CC + (col % CC)
                           : (size_t)row * N + col;
          if (res) v += res[off];
          Cf[off] = v;
        }
        if (Chi) {
          size_t o2 = (size_t)row * N + col;
          unsigned short hb, lb;
          split2(v, hb, lb);
          Chi[o2] = hb;
          if (Clo) Clo[o2] = lb;
        }
      }
    }
}

// ---------------- split-K combine (bias/act/rowmask/res epilogue) ----------------
__global__ __launch_bounds__(256) void gemm_combine_kernel(
    const float* __restrict__ part, int ksplit, int M, int N,
    const float* __restrict__ bias, float* __restrict__ Cf,
    unsigned short* __restrict__ Chi, unsigned short* __restrict__ Clo,
    int act, const float* __restrict__ res, const float* __restrict__ rowmask) {
  int i = blockIdx.x * 256 + threadIdx.x;
  if (i >= M * N) return;
  int row = i / N, col = i - row * N;
  float v = 0.f;
  for (int s = 0; s < ksplit; s++) v += part[(size_t)s * M * N + i];
  if (bias) v += bias[col];
  if (act == 1) v = 0.5f * v * (1.f + erff(v * 0.70710678118654752f));
  if (rowmask) v *= rowmask[row];
  if (Cf) {
    if (res) v += res[i];
    Cf[i] = v;
  }
  if (Chi) {
    unsigned short hb, lb;
    split2(v, hb, lb);
    Chi[i] = hb;
    if (Clo) Clo[i] = lb;
  }
}

// ---------------- SDPA split-K from qkv bf16 planes: per (h, tile-pair) partial ------
__global__ __launch_bounds__(256) void sdpa_part_kernel(
    const unsigned short* __restrict__ qkvh, const unsigned short* __restrict__ qkvl,
    float* __restrict__ oPart, float* __restrict__ mPart, float* __restrict__ lPart) {
  int h = blockIdx.x;
  int p = blockIdx.y;  // 0..35 lower-triangle pair
  int bt = 0, base = 0;
  while (p >= base + bt + 1) { base += bt + 1; bt++; }
  int st = p - base;
  int t0 = bt * 64, s0 = st * 64;
  int tid = threadIdx.x, lane = tid & 63, w = tid >> 6;
  int lr = lane & 15, ksub = (lane >> 4) * 8;
  const int hDD = h * DD;

  __shared__ unsigned short qHi[64 * 64], qLo[64 * 64];
  __shared__ unsigned short kHi[64 * 64], kLo[64 * 64];
  __shared__ unsigned short bufP[64 * 64], bufV[64 * 64];

  int lrow = tid >> 2, lq = tid & 3;
  {
    size_t qoff = (size_t)(t0 + lrow) * (3 * CC) + hDD + lq * 16;
    size_t koff = (size_t)(s0 + lrow) * (3 * CC) + CC + hDD + lq * 16;
    int d0 = lrow * 64 + (((lq * 2) ^ (lrow & 7)) << 3);
    int d1 = lrow * 64 + (((lq * 2 + 1) ^ (lrow & 7)) << 3);
    *(ushort8v*)&qHi[d0] = *(const ushort8v*)&qkvh[qoff];
    *(ushort8v*)&qHi[d1] = *(const ushort8v*)&qkvh[qoff + 8];
    *(ushort8v*)&qLo[d0] = *(const ushort8v*)&qkvl[qoff];
    *(ushort8v*)&qLo[d1] = *(const ushort8v*)&qkvl[qoff + 8];
    *(ushort8v*)&kHi[d0] = *(const ushort8v*)&qkvh[koff];
    *(ushort8v*)&kHi[d1] = *(const ushort8v*)&qkvh[koff + 8];
    *(ushort8v*)&kLo[d0] = *(const ushort8v*)&qkvl[koff];
    *(ushort8v*)&kLo[d1] = *(const ushort8v*)&qkvl[koff + 8];
  }
  // V stage: direct hi copy, diagonal rotation avoids conflicts
#pragma unroll
  for (int r = 0; r < 16; r++) {
    int sl = w * 16 + ((r + (lane >> 3)) & 15);
    bufV[swz(lane, sl)] = qkvh[(size_t)(s0 + sl) * (3 * CC) + 2 * CC + hDD + lane];
  }
  __syncthreads();
  // S = Q K^T
  f32x4 acc[4];
#pragma unroll
  for (int nt = 0; nt < 4; nt++) acc[nt] = (f32x4){0.f, 0.f, 0.f, 0.f};
  {
    bf16x8 ah[2], al[2];
#pragma unroll
    for (int kb = 0; kb < 2; kb++) {
      int off = swz(w * 16 + lr, kb * 32 + ksub);
      ah[kb] = *(const bf16x8*)&qHi[off];
      al[kb] = *(const bf16x8*)&qLo[off];
    }
#pragma unroll
    for (int nt = 0; nt < 4; nt++)
#pragma unroll
      for (int kb = 0; kb < 2; kb++) {
        int off = swz(nt * 16 + lr, kb * 32 + ksub);
        bf16x8 bh = *(const bf16x8*)&kHi[off];
        bf16x8 bl = *(const bf16x8*)&kLo[off];
        acc[nt] = __builtin_amdgcn_mfma_f32_16x16x32_bf16(ah[kb], bh, acc[nt], 0, 0, 0);
        acc[nt] = __builtin_amdgcn_mfma_f32_16x16x32_bf16(ah[kb], bl, acc[nt], 0, 0, 0);
        acc[nt] = __builtin_amdgcn_mfma_f32_16x16x32_bf16(al[kb], bh, acc[nt], 0, 0, 0);
      }
  }
  // per-row tile softmax numerator (exp relative to tile max)
  int pbase = (h * NPAIR + p) * 64;
#pragma unroll
  for (int q = 0; q < 4; q++) {
    int rloc = w * 16 + (lane >> 4) * 4 + q;
    float tm = -INFINITY;
#pragma unroll
    for (int nt = 0; nt < 4; nt++) {
      float v = acc[nt][q] * 0.125f;
      if (st == bt && nt * 16 + lr > rloc) v = -INFINITY;
      acc[nt][q] = v;
      tm = fmaxf(tm, v);
    }
#pragma unroll
    for (int off = 1; off < 16; off <<= 1) tm = fmaxf(tm, __shfl_xor(tm, off));
    float ps = 0.f;
#pragma unroll
    for (int nt = 0; nt < 4; nt++) {
      float e = __expf(acc[nt][q] - tm);
      acc[nt][q] = e;
      ps += e;
    }
#pragma unroll
    for (int off = 1; off < 16; off <<= 1) ps += __shfl_xor(ps, off);
    if (lr == 0) {
      mPart[pbase + rloc] = tm;
      lPart[pbase + rloc] = ps;
    }
  }
  // P -> LDS bf16
#pragma unroll
  for (int nt = 0; nt < 4; nt++)
#pragma unroll
    for (int q = 0; q < 4; q++) {
      int row = w * 16 + (lane >> 4) * 4 + q;
      int col = nt * 16 + lr;
      bufP[swz(row, col)] = f32_to_bf16_rne(acc[nt][q]);
    }
  __syncthreads();
  // O_part = P V^T
  f32x4 o[4];
#pragma unroll
  for (int nt = 0; nt < 4; nt++) o[nt] = (f32x4){0.f, 0.f, 0.f, 0.f};
  {
    bf16x8 pf[2];
#pragma unroll
    for (int kb = 0; kb < 2; kb++)
      pf[kb] = *(const bf16x8*)&bufP[swz(w * 16 + lr, kb * 32 + ksub)];
#pragma unroll
    for (int nt = 0; nt < 4; nt++)
#pragma unroll
      for (int kb = 0; kb < 2; kb++) {
        bf16x8 bv = *(const bf16x8*)&bufV[swz(nt * 16 + lr, kb * 32 + ksub)];
        o[nt] = __builtin_amdgcn_mfma_f32_16x16x32_bf16(pf[kb], bv, o[nt], 0, 0, 0);
      }
  }
  float* obase = oPart + ((size_t)(h * NPAIR + p) << 12);
#pragma unroll
  for (int nt = 0; nt < 4; nt++)
#pragma unroll
    for (int q = 0; q < 4; q++) {
      int row = w * 16 + (lane >> 4) * 4 + q;
      int col = nt * 16 + lr;
      obase[row * 64 + col] = o[nt][q];
    }
}

// ---------------- SDPA combine: one thread per (t-row, d) element ----------------
__global__ __launch_bounds__(256) void sdpa_combine_kernel(
    const float* __restrict__ oPart, const float* __restrict__ mPart,
    const float* __restrict__ lPart,
    unsigned short* __restrict__ yhi, unsigned short* __restrict__ ylo) {
  int h = blockIdx.x, bt = blockIdx.y;
  int base = bt * (bt + 1) / 2;
  int n = bt + 1;
  int tid = threadIdx.x;
  int d = tid & 63;
  int r = blockIdx.z * 4 + (tid >> 6);  // 4 rows per block
  int t0 = bt * 64;
  float mg = -INFINITY;
  for (int s = 0; s < n; s++)
    mg = fmaxf(mg, mPart[(h * NPAIR + base + s) * 64 + r]);
  float lg = 0.f, oacc = 0.f;
  for (int s = 0; s < n; s++) {
    int pi = h * NPAIR + base + s;
    float sc = __expf(mPart[pi * 64 + r] - mg);
    lg += sc * lPart[pi * 64 + r];
    oacc += sc * oPart[((size_t)pi << 12) + r * 64 + d];
  }
  float v = oacc / lg;
  unsigned short hb, lb;
  split2(v, hb, lb);
  yhi[(size_t)(t0 + r) * CC + h * DD + d] = hb;
  ylo[(size_t)(t0 + r) * CC + h * DD + d] = lb;
}

// ---------------- HOA score GEMM from bf16 planes [T][5CC] ----------------
__global__ __launch_bounds__(256) void score_gemm_kernel(
    const unsigned short* __restrict__ ph, const unsigned short* __restrict__ pl,
    float* __restrict__ scores) {
  if (blockIdx.x > blockIdx.y) return;
  int bh = blockIdx.z;
  int br = bh >= HH ? 1 : 0;
  int h = bh - br * HH;
  int s0 = blockIdx.x * 64, t0 = blockIdx.y * 64;
  int hDD = h * DD;
  int kcol = (1 + br) * CC + hDD;
  __shared__ unsigned short AsH[64 * 64], AsL[64 * 64], BsH[64 * 64], BsL[64 * 64];
  int tid = threadIdx.x, lane = tid & 63, wave = tid >> 6;
  int wr = wave >> 1, wc = wave & 1, lr = lane & 15;
  int ksub = (lane >> 4) * 8;
  int lrow = tid >> 2, lq = tid & 3;
  {
    size_t aoff = (size_t)(t0 + lrow) * PW + hDD + lq * 16;
    size_t boff = (size_t)(s0 + lrow) * PW + kcol + lq * 16;
    int d0 = lrow * 64 + (((lq * 2) ^ (lrow & 7)) << 3);
    int d1 = lrow * 64 + (((lq * 2 + 1) ^ (lrow & 7)) << 3);
    *(ushort8v*)&AsH[d0] = *(const ushort8v*)&ph[aoff];
    *(ushort8v*)&AsH[d1] = *(const ushort8v*)&ph[aoff + 8];
    *(ushort8v*)&AsL[d0] = *(const ushort8v*)&pl[aoff];
    *(ushort8v*)&AsL[d1] = *(const ushort8v*)&pl[aoff + 8];
    *(ushort8v*)&BsH[d0] = *(const ushort8v*)&ph[boff];
    *(ushort8v*)&BsH[d1] = *(const ushort8v*)&ph[boff + 8];
    *(ushort8v*)&BsL[d0] = *(const ushort8v*)&pl[boff];
    *(ushort8v*)&BsL[d1] = *(const ushort8v*)&pl[boff + 8];
  }
  __syncthreads();
  f32x4 acc[2][2];
#pragma unroll
  for (int i = 0; i < 2; i++)
#pragma unroll
    for (int j = 0; j < 2; j++) acc[i][j] = (f32x4){0.f, 0.f, 0.f, 0.f};
#pragma unroll
  for (int kb = 0; kb < 2; kb++) {
    int kloc = kb * 32 + ksub;
    bf16x8 ah[2], al[2], bh_[2], bl[2];
#pragma unroll
    for (int i = 0; i < 2; i++) {
      int m = wr * 32 + i * 16 + lr;
      int off = swz(m, kloc);
      ah[i] = *(const bf16x8*)&AsH[off];
      al[i] = *(const bf16x8*)&AsL[off];
    }
#pragma unroll
    for (int j = 0; j < 2; j++) {
      int n = wc * 32 + j * 16 + lr;
      int off = swz(n, kloc);
      bh_[j] = *(const bf16x8*)&BsH[off];
      bl[j] = *(const bf16x8*)&BsL[off];
    }
#pragma unroll
    for (int i = 0; i < 2; i++)
#pragma unroll
      for (int j = 0; j < 2; j++) {
        acc[i][j] = __builtin_amdgcn_mfma_f32_16x16x32_bf16(ah[i], bh_[j], acc[i][j], 0, 0, 0);
        acc[i][j] = __builtin_amdgcn_mfma_f32_16x16x32_bf16(ah[i], bl[j], acc[i][j], 0, 0, 0);
        acc[i][j] = __builtin_amdgcn_mfma_f32_16x16x32_bf16(al[i], bh_[j], acc[i][j], 0, 0, 0);
      }
  }
#pragma unroll
  for (int i = 0; i < 2; i++)
#pragma unroll
    for (int j = 0; j < 2; j++)
#pragma unroll
      for (int q = 0; q < 4; q++) {
        int tt = t0 + wr * 32 + i * 16 + (lane >> 4) * 4 + q;
        int ss = s0 + wc * 32 + j * 16 + lr;
        scores[((size_t)bh * TT + tt) * TT + ss] = acc[i][j][q];
      }
}

// ---------------- low-LDS shuffle primitives (DPP / ds_swizzle) ----------
template<int CTRL>
__device__ __forceinline__ u64 dpp64(u64 x) {
  unsigned lo = (unsigned)__builtin_amdgcn_update_dpp(
      (int)(unsigned)x, (int)(unsigned)x, CTRL, 0xF, 0xF, true);
  unsigned hi = (unsigned)__builtin_amdgcn_update_dpp(
      (int)(unsigned)(x >> 32), (int)(unsigned)(x >> 32), CTRL, 0xF, 0xF, true);
  return ((u64)hi << 32) | lo;
}
template<int MASK>
__device__ __forceinline__ u64 swz64(u64 x) {
  unsigned lo = (unsigned)__builtin_amdgcn_ds_swizzle((int)(unsigned)x, (MASK << 10) | 0x1F);
  unsigned hi = (unsigned)__builtin_amdgcn_ds_swizzle((int)(unsigned)(x >> 32), (MASK << 10) | 0x1F);
  return ((u64)hi << 32) | lo;
}
__device__ __forceinline__ u64 cas_dir(u64 x, u64 y, bool low) {
  bool take_y = low ? (y > x) : (y < x);
  return take_y ? y : x;
}
__device__ __forceinline__ u64 sort64m(u64 x, int lane) {
  x = cas_dir(x, dpp64<0xB1>(x), (lane & 1) == 0);
  x = cas_dir(x, dpp64<0x1B>(x), (lane & 2) == 0);
  x = cas_dir(x, dpp64<0xB1>(x), (lane & 1) == 0);
  x = cas_dir(x, dpp64<0x141>(x), (lane & 4) == 0);
  x = cas_dir(x, dpp64<0x4E>(x), (lane & 2) == 0);
  x = cas_dir(x, dpp64<0xB1>(x), (lane & 1) == 0);
  x = cas_dir(x, dpp64<0x140>(x), (lane & 8) == 0);
  x = cas_dir(x, swz64<4>(x), (lane & 4) == 0);
  x = cas_dir(x, dpp64<0x4E>(x), (lane & 2) == 0);
  x = cas_dir(x, dpp64<0xB1>(x), (lane & 1) == 0);
  x = cas_dir(x, swz64<31>(x), (lane & 16) == 0);
  x = cas_dir(x, swz64<8>(x), (lane & 8) == 0);
  x = cas_dir(x, swz64<4>(x), (lane & 4) == 0);
  x = cas_dir(x, dpp64<0x4E>(x), (lane & 2) == 0);
  x = cas_dir(x, dpp64<0xB1>(x), (lane & 1) == 0);
  x = cas_dir(x, __shfl_xor(x, 63), (lane & 32) == 0);
  x = cas_dir(x, swz64<16>(x), (lane & 16) == 0);
  x = cas_dir(x, swz64<8>(x), (lane & 8) == 0);
  x = cas_dir(x, swz64<4>(x), (lane & 4) == 0);
  x = cas_dir(x, dpp64<0x4E>(x), (lane & 2) == 0);
  x = cas_dir(x, dpp64<0xB1>(x), (lane & 1) == 0);
  return x;
}
__device__ __forceinline__ u64 merge64m(u64 x, int lane) {
  x = cas_dir(x, __shfl_xor(x, 32), (lane & 32) == 0);
  x = cas_dir(x, swz64<16>(x), (lane & 16) == 0);
  x = cas_dir(x, swz64<8>(x), (lane & 8) == 0);
  x = cas_dir(x, swz64<4>(x), (lane & 4) == 0);
  x = cas_dir(x, dpp64<0x4E>(x), (lane & 2) == 0);
  x = cas_dir(x, dpp64<0xB1>(x), (lane & 1) == 0);
  return x;
}
__device__ __forceinline__ u64 merge2m(u64 a, u64 b, int lane) {
  u64 rev = __shfl_xor(b, 63);
  u64 run = a > rev ? a : rev;
  return merge64m(run, lane);
}
__device__ __forceinline__ u64 make_key(float v, int s, int t) {
  unsigned sv = 0u;
  if (s <= t) {
    unsigned u = __float_as_uint(v);
    sv = (u & 0x80000000u) ? ~u : (u | 0x80000000u);
  }
  return ((u64)sv << 32) | (unsigned)(~s);
}

// ---------------- wave top-64 selection: chunk-skip + tree merge (1 row/wave) --------
__global__ __launch_bounds__(256) void topk_select_kernel(
    const float* __restrict__ scores, int* __restrict__ idx1, int* __restrict__ idx2) {
  int tid = threadIdx.x, lane = tid & 63, w = tid >> 6;
  int row = blockIdx.x * 4 + w;
  int br = row >= (HH * TT) ? 1 : 0;
  int rem = row - br * (HH * TT);
  int h = rem >> 9, t = rem & (TT - 1);
  const float* sr = scores + ((size_t)(br * HH + h) * TT + t) * TT;
  int nc = (t >> 6) + 1;
  u64 c[8];
#pragma unroll
  for (int e = 0; e < 8; e++) {
    if (e < nc)
      c[e] = sort64m(make_key(sr[e * 64 + lane], e * 64 + lane, t), lane);
    else
      c[e] = (u64)(unsigned)(~(e * 64 + lane));
  }
  u64 l10 = (t >= 64)  ? merge2m(c[0], c[1], lane) : c[0];
  u64 l11 = (t >= 192) ? merge2m(c[2], c[3], lane) : c[2];
  u64 l12 = (t >= 320) ? merge2m(c[4], c[5], lane) : c[4];
  u64 l13 = (t >= 448) ? merge2m(c[6], c[7], lane) : c[6];
  u64 l20 = (t >= 128) ? merge2m(l10, l11, lane) : l10;
  u64 l21 = (t >= 384) ? merge2m(l12, l13, lane) : l12;
  u64 res = (t >= 256) ? merge2m(l20, l21, lane) : l20;
  unsigned myidx = ~(unsigned)res;
  unsigned outv = __shfl(myidx, min(lane, t));
  int* idxout = (br ? idx2 : idx1) + ((size_t)h * TT + t) * KKEEP;
  idxout[lane] = (int)outv;
}

// ---------------- register bitonic sort of 512 u64 keys across one wave (gate) -------
__device__ __forceinline__ u64 cas_u64(u64 x, int j, bool dirmax, int lane) {
  u64 y = __shfl_xor(x, j);
  bool lower = (lane & j) == 0;
  bool keepmax = (dirmax == lower);
  return (keepmax ? (y > x) : (y < x)) ? y : x;
}
__device__ __forceinline__ void sort512(u64* key, int lane) {
#pragma unroll
  for (int k = 2; k <= 512; k <<= 1) {
#pragma unroll
    for (int j = k >> 1; j > 0; j >>= 1) {
      if (j < 64) {
        bool lower = (lane & j) == 0;
#pragma unroll
        for (int e = 0; e < 8; e++) {
          bool desc = ((((e << 6) | lane) & k) == 0);
          u64 part = __shfl_xor(key[e], j);
          bool wantmax = (desc == lower);
          key[e] = (wantmax ? (part > key[e]) : (part < key[e])) ? part : key[e];
        }
      } else {
        int m = j >> 6;
#pragma unroll
        for (int e = 0; e < 8; e++) {
          if ((e & m) == 0) {
            int e2 = e | m;
            bool desc = ((((e << 6) | lane) & k) == 0);
            u64 a = key[e], b = key[e2];
            u64 mx = a > b ? a : b;
            u64 mn = a > b ? b : a;
            key[e] = desc ? mx : mn;
            key[e2] = desc ? mn : mx;
          }
        }
      }
    }
  }
}

// ---------------- HOA core: MFMA from bf16 planes (vectorized staging) ----------
__global__ __launch_bounds__(256) void hoa_core_kernel(
    const unsigned short* __restrict__ ph, const unsigned short* __restrict__ pl,
    const int* __restrict__ idx1, const int* __restrict__ idx2,
    unsigned short* __restrict__ hcohi) {
  int h = blockIdx.x, t = blockIdx.y, tid = threadIdx.x;
  int lane = tid & 63, w = tid >> 6;
  int lr = lane & 15;
  int ksub = (lane >> 4) * 8;
  const int hDD = h * DD;

  __shared__ unsigned short bufA[64 * 64];
  __shared__ unsigned short bufB[64 * 64];
  __shared__ unsigned short v1s[64 * 68];
  __shared__ float red[4 * 64];
  __shared__ int i1s[64], i2s[64];

  if (tid < 64) {
    i1s[tid] = idx1[(h * TT + t) * KKEEP + tid] * PW + CC + hDD;      // K1 plane offset
    i2s[tid] = idx2[(h * TT + t) * KKEEP + tid] * PW + 2 * CC + hDD;  // K2 plane offset
  }
  __syncthreads();

  // vectorized staging: lane covers 2 adjacent k-elements; 32 lanes/row, 2 rows/iter
  int half = lane >> 5;
  int c2 = (lane & 31) * 2;
  size_t qbase = (size_t)t * PW + hDD;
  float qf0 = bf16_to_f32(ph[qbase + c2]) + bf16_to_f32(pl[qbase + c2]);
  float qf1 = bf16_to_f32(ph[qbase + c2 + 1]) + bf16_to_f32(pl[qbase + c2 + 1]);
#pragma unroll
  for (int r = 0; r < 8; r++) {
    int j = w * 16 + r * 2 + half;
    unsigned k1p = *(const unsigned*)&ph[i1s[j] + c2];
    unsigned k2p = *(const unsigned*)&ph[i2s[j] + c2];
    unsigned v1p = *(const unsigned*)&ph[i1s[j] + 2 * CC + c2];
    unsigned short a0 = f32_to_bf16_rne(bf16_to_f32((unsigned short)(k1p & 0xFFFFu)) * qf0);
    unsigned short a1 = f32_to_bf16_rne(bf16_to_f32((unsigned short)(k1p >> 16)) * qf1);
    int off = swz(j, c2);
    *(unsigned*)&bufA[off] = (unsigned)a0 | ((unsigned)a1 << 16);
    *(unsigned*)&bufB[off] = k2p;
    *(unsigned*)&v1s[j * 68 + c2] = v1p;
  }
  __syncthreads();

  f32x4 acc[4];
#pragma unroll
  for (int nt = 0; nt < 4; nt++) acc[nt] = (f32x4){0.f, 0.f, 0.f, 0.f};
  {
    bf16x8 af[2];
#pragma unroll
    for (int kb = 0; kb < 2; kb++)
      af[kb] = *(const bf16x8*)&bufA[swz(w * 16 + lr, kb * 32 + ksub)];
#pragma unroll
    for (int nt = 0; nt < 4; nt++)
#pragma unroll
      for (int kb = 0; kb < 2; kb++) {
        bf16x8 bf = *(const bf16x8*)&bufB[swz(nt * 16 + lr, kb * 32 + ksub)];
        acc[nt] = __builtin_amdgcn_mfma_f32_16x16x32_bf16(af[kb], bf, acc[nt], 0, 0, 0);
      }
  }
#pragma unroll
  for (int q = 0; q < 4; q++) {
    float m = -INFINITY;
#pragma unroll
    for (int nt = 0; nt < 4; nt++) {
      acc[nt][q] *= 0.125f;
      m = fmaxf(m, acc[nt][q]);
    }
#pragma unroll
    for (int off = 1; off < 16; off <<= 1) m = fmaxf(m, __shfl_xor(m, off));
    float s = 0.f;
#pragma unroll
    for (int nt = 0; nt < 4; nt++) {
      float e = __expf(acc[nt][q] - m);
      acc[nt][q] = e;
      s += e;
    }
#pragma unroll
    for (int off = 1; off < 16; off <<= 1) s += __shfl_xor(s, off);
    float inv = 1.f / s;
#pragma unroll
    for (int nt = 0; nt < 4; nt++) acc[nt][q] *= inv;
  }
  __syncthreads();

#pragma unroll
  for (int nt = 0; nt < 4; nt++)
#pragma unroll
    for (int q = 0; q < 4; q++) {
      int row = w * 16 + (lane >> 4) * 4 + q;
      int col = nt * 16 + lr;
      bufA[swz(row, col)] = f32_to_bf16_rne(acc[nt][q]);
    }
  // V2 transpose gather: even-pair diagonal rotation, u32 writes
#pragma unroll
  for (int r = 0; r < 8; r++) {
    int kk = w * 16 + ((r * 2 + ((lane >> 3) * 2)) & 15);
    unsigned short b0 = ph[i2s[kk] + 2 * CC + lane];
    unsigned short b1 = ph[i2s[kk + 1] + 2 * CC + lane];
    int off = swz(lane, kk);
    *(unsigned*)&bufB[off] = (unsigned)b0 | ((unsigned)b1 << 16);
  }
  __syncthreads();

  f32x4 acc2[4];
#pragma unroll
  for (int nt = 0; nt < 4; nt++) acc2[nt] = (f32x4){0.f, 0.f, 0.f, 0.f};
  {
    bf16x8 af[2];
#pragma unroll
    for (int kb = 0; kb < 2; kb++)
      af[kb] = *(const bf16x8*)&bufA[swz(w * 16 + lr, kb * 32 + ksub)];
#pragma unroll
    for (int nt = 0; nt < 4; nt++)
#pragma unroll
      for (int kb = 0; kb < 2; kb++) {
        bf16x8 bf = *(const bf16x8*)&bufB[swz(nt * 16 + lr, kb * 32 + ksub)];
        acc2[nt] = __builtin_amdgcn_mfma_f32_16x16x32_bf16(af[kb], bf, acc2[nt], 0, 0, 0);
      }
  }
#pragma unroll
  for (int nt = 0; nt < 4; nt++) {
    float p = 0.f;
#pragma unroll
    for (int q = 0; q < 4; q++) {
      int row = w * 16 + (lane >> 4) * 4 + q;
      int col = lr + 16 * nt;
      p += acc2[nt][q] * bf16_to_f32(v1s[row * 68 + col]);
    }
    p += __shfl_xor(p, 16);
    p += __shfl_xor(p, 32);
    if (lane < 16) red[w * 64 + 16 * nt + lr] = p;
  }
  __syncthreads();
  if (tid < 64) {
    float o = red[tid] + red[64 + tid] + red[128 + tid] + red[192 + tid];
    hcohi[t * CC + hDD + tid] = f32_to_bf16_rne(o);
  }
}

// ---------------- gate mask ----------------
__global__ void gate_mask_kernel(const float* __restrict__ scores, float* __restrict__ mask) {
  int lane = threadIdx.x;  // 64 threads, one wave
  u64 key[8];
#pragma unroll
  for (int e = 0; e < 8; e++) {
    int s = e * 64 + lane;
    unsigned uu = __float_as_uint(scores[s]);
    unsigned sv = (uu & 0x80000000u) ? ~uu : (uu | 0x80000000u);
    key[e] = ((u64)sv << 32) | (unsigned)(~s);
    mask[s] = 0.f;
  }
  __asm__ volatile("s_waitcnt vmcnt(0)" ::: "memory");
  sort512(key, lane);
#pragma unroll
  for (int e = 0; e < 2; e++) mask[(int)(~(unsigned)key[e])] = 1.f;
}

// ---------------- launcher ----------------
extern "C" void kernel_launch(void* const* d_in, const int* in_sizes, int n_in,
                              void* d_out, int out_size, void* d_ws, size_t ws_size,
                              hipStream_t stream) {
  const float* x      = (const float*)d_in[0];
  const float* ln1_w  = (const float*)d_in[1];
  const float* ln1_b  = (const float*)d_in[2];
  const float* qkv_w  = (const float*)d_in[3];
  const float* qkv_b  = (const float*)d_in[4];
  const float* atto_w = (const float*)d_in[5];
  const float* atto_b = (const float*)d_in[6];
  const float* lnh_w  = (const float*)d_in[7];
  const float* lnh_b  = (const float*)d_in[8];
  const float* hq_w   = (const float*)d_in[9];
  const float* hk1_w  = (const float*)d_in[10];
  const float* hk2_w  = (const float*)d_in[11];
  const float* hv1_w  = (const float*)d_in[12];
  const float* hv2_w  = (const float*)d_in[13];
  const float* ho_w   = (const float*)d_in[14];
  const float* gate_w = (const float*)d_in[15];
  const float* gate_b = (const float*)d_in[16];
  const float* ln2_w  = (const float*)d_in[17];
  const float* ln2_b  = (const float*)d_in[18];
  const float* fc_w   = (const float*)d_in[19];
  const float* fc_b   = (const float*)d_in[20];
  const float* pr_w   = (const float*)d_in[21];
  const float* pr_b   = (const float*)d_in[22];
  float* out = (float*)d_out;

  // workspace carve-up
  char* cur = (char*)d_ws;
  auto alloc = [&](size_t bytes) {
    char* p = cur;
    cur += (bytes + 255) & ~(size_t)255;
    return p;
  };
  float* x1   = (float*)alloc((size_t)NTCE * 4);
  float* x2   = (float*)alloc((size_t)NTCE * 4);
  float* scores = (float*)alloc(TT * 4);
  float* maskb  = (float*)alloc(TT * 4);
  int* idx1 = (int*)alloc((size_t)HH * TT * KKEEP * 4);
  int* idx2 = (int*)alloc((size_t)HH * TT * KKEEP * 4);
  float* hscores = (float*)alloc((size_t)2 * HH * TT * TT * 4);  // 25 MB
  float* oPart = (float*)alloc((size_t)HH * NPAIR * 64 * 64 * 4);  // 7.1 MB
  float* mPart = (float*)alloc((size_t)HH * NPAIR * 64 * 4);
  float* lPart = (float*)alloc((size_t)HH * NPAIR * 64 * 4);
  float* gpart = (float*)alloc((size_t)2 * TT * 4 * CC * 4);  // split-K partials
  // activation planes
  unsigned short* hHi    = (unsigned short*)alloc((size_t)NTCE * 2);
  unsigned short* hLo    = (unsigned short*)alloc((size_t)NTCE * 2);
  unsigned short* qkvHi  = (unsigned short*)alloc((size_t)3 * NTCE * 2);
  unsigned short* qkvLo  = (unsigned short*)alloc((size_t)3 * NTCE * 2);
  unsigned short* yHi    = (unsigned short*)alloc((size_t)NTCE * 2);
  unsigned short* yLo    = (unsigned short*)alloc((size_t)NTCE * 2);
  unsigned short* hoinHi = (unsigned short*)alloc((size_t)NTCE * 2);
  unsigned short* hoinLo = (unsigned short*)alloc((size_t)NTCE * 2);
  unsigned short* hoaPh  = (unsigned short*)alloc((size_t)TT * PW * 2);  // [T][5CC] hi
  unsigned short* hoaPl  = (unsigned short*)alloc((size_t)TT * PW * 2);  // [T][5CC] lo
  unsigned short* h2Hi   = (unsigned short*)alloc((size_t)NTCE * 2);
  unsigned short* h2Lo   = (unsigned short*)alloc((size_t)NTCE * 2);
  unsigned short* hcoHi  = (unsigned short*)alloc((size_t)NTCE * 2);
  unsigned short* fcbHi  = (unsigned short*)alloc((size_t)4 * NTCE * 2);
  // weight planes (transposed [N][K])
  const size_t WSQ = (size_t)CC * CC;
  unsigned short* qkvT_h = (unsigned short*)alloc((size_t)CC * 3 * CC * 2);
  unsigned short* qkvT_l = (unsigned short*)alloc((size_t)CC * 3 * CC * 2);
  unsigned short* attoT_h = (unsigned short*)alloc(WSQ * 2);
  unsigned short* attoT_l = (unsigned short*)alloc(WSQ * 2);
  unsigned short* hoaT_h = (unsigned short*)alloc(5 * WSQ * 2);
  unsigned short* hoaT_l = (unsigned short*)alloc(5 * WSQ * 2);
  unsigned short* hoT_h = (unsigned short*)alloc(WSQ * 2);
  unsigned short* hoT_l = (unsigned short*)alloc(WSQ * 2);
  unsigned short* fcT_h = (unsigned short*)alloc((size_t)CC * 4 * CC * 2);
  unsigned short* fcT_l = (unsigned short*)alloc((size_t)CC * 4 * CC * 2);
  unsigned short* prT_h = (unsigned short*)alloc((size_t)CC * 4 * CC * 2);
  unsigned short* prT_l = (unsigned short*)alloc((size_t)CC * 4 * CC * 2);

  // weight split jobs
  WSplitArgs wa;
  int tcur = 0;
  auto addw = [&](int i, const float* s, unsigned short* hi, unsigned short* lo, int K, int N) {
    wa.src[i] = s; wa.hi[i] = hi; wa.lo[i] = lo;
    wa.K[i] = K; wa.N[i] = N; wa.tstart[i] = tcur;
    tcur += (N / 64) * (K / 64);
  };
  addw(0, qkv_w, qkvT_h, qkvT_l, CC, 3 * CC);
  addw(1, atto_w, attoT_h, attoT_l, CC, CC);
  addw(2, hq_w,  hoaT_h + 0 * WSQ, hoaT_l + 0 * WSQ, CC, CC);
  addw(3, hk1_w, hoaT_h + 1 * WSQ, hoaT_l + 1 * WSQ, CC, CC);
  addw(4, hk2_w, hoaT_h + 2 * WSQ, hoaT_l + 2 * WSQ, CC, CC);
  addw(5, hv1_w, hoaT_h + 3 * WSQ, hoaT_l + 3 * WSQ, CC, CC);
  addw(6, hv2_w, hoaT_h + 4 * WSQ, hoaT_l + 4 * WSQ, CC, CC);
  addw(7, ho_w, hoT_h, hoT_l, CC, CC);
  addw(8, fc_w, fcT_h, fcT_l, CC, 4 * CC);
  addw(9, pr_w, prT_h, prT_l, 4 * CC, CC);

  dim3 blk(256);
  const float* nullf = nullptr;
  unsigned short* nullu = nullptr;

  hipLaunchKernelGGL(wsplitT_kernel, dim3(tcur), blk, 0, stream, wa);
  // LN1 -> h planes
  hipLaunchKernelGGL(ln_bf_kernel, dim3(TT), blk, 0, stream, x, ln1_w, ln1_b,
                     hHi, hLo, nullf, nullf, (float*)nullptr);
  // QKV (3-pass exact) -> bf16 planes directly
  hipLaunchKernelGGL(gemm_bf, dim3(36, 8, 1), blk, 0, stream, hHi, hLo, qkvT_h, qkvT_l,
                     qkv_b, (float*)nullptr, qkvHi, qkvLo,
                     TT, 3 * CC, CC, 0, 0, nullf, nullf, (float*)nullptr, 3);
  // SDPA split-K (from planes)
  hipLaunchKernelGGL(sdpa_part_kernel, dim3(HH, NPAIR), blk, 0, stream,
                     qkvHi, qkvLo, oPart, mPart, lPart);
  hipLaunchKernelGGL(sdpa_combine_kernel, dim3(HH, 8, 16), blk, 0, stream,
                     oPart, mPart, lPart, yHi, yLo);
  // atto (split-K 2, 3-pass) + residual -> x1
  hipLaunchKernelGGL(gemm_bf, dim3(12, 8, 2), blk, 0, stream, yHi, yLo, attoT_h, attoT_l,
                     nullf, (float*)nullptr, nullu, nullu,
                     TT, CC, CC, 0, 0, nullf, nullf, gpart, 3);
  hipLaunchKernelGGL(gemm_combine_kernel, dim3((NTCE + 255) / 256), blk, 0, stream,
                     gpart, 2, TT, CC, atto_b, x1,
                     nullu, nullu, 0, x, nullf);
  // LNh -> hoin planes + fused gate scores
  hipLaunchKernelGGL(ln_bf_kernel, dim3(TT), blk, 0, stream, x1, lnh_w, lnh_b,
                     hoinHi, hoinLo, gate_w, gate_b, scores);
  // gate mask
  hipLaunchKernelGGL(gate_mask_kernel, dim3(1), dim3(64), 0, stream, scores, maskb);
  // 5 HOA projections merged (3-pass exact) -> bf16 plane pair [T][5CC]
  hipLaunchKernelGGL(gemm_bf, dim3(60, 8, 1), blk, 0, stream, hoinHi, hoinLo, hoaT_h, hoaT_l,
                     nullf, (float*)nullptr, hoaPh, hoaPl,
                     TT, PW, CC, 0, 0, nullf, nullf, (float*)nullptr, 3);
  // HOA scores (both branches) + wave top-64 selection
  hipLaunchKernelGGL(score_gemm_kernel, dim3(8, 8, 2 * HH), blk, 0, stream,
                     hoaPh, hoaPl, hscores);
  hipLaunchKernelGGL(topk_select_kernel, dim3(2 * HH * TT / 4), blk, 0, stream,
                     hscores, idx1, idx2);
  // HOA core (bf16 planes, vectorized staging) -> hco hi plane
  hipLaunchKernelGGL(hoa_core_kernel, dim3(HH, TT), blk, 0, stream,
                     hoaPh, hoaPl, idx1, idx2, hcoHi);
  // ho GEMM (split-K 2, single-pass bf16) with gate-mask + residual -> x2
  hipLaunchKernelGGL(gemm_bf, dim3(12, 8, 2), blk, 0, stream, hcoHi, nullu, hoT_h, nullu,
                     nullf, (float*)nullptr, nullu, nullu,
                     TT, CC, CC, 0, 0, nullf, nullf, gpart, 1);
  hipLaunchKernelGGL(gemm_combine_kernel, dim3((NTCE + 255) / 256), blk, 0, stream,
                     gpart, 2, TT, CC, nullf, x2,
                     nullu, nullu, 0, x1, maskb);
  // LN2 -> h2 planes
  hipLaunchKernelGGL(ln_bf_kernel, dim3(TT), blk, 0, stream, x2, ln2_w, ln2_b,
                     h2Hi, h2Lo, nullf, nullf, (float*)nullptr);
  // fc (single-pass bf16) + gelu -> fcb hi plane
  hipLaunchKernelGGL(gemm_bf, dim3(48, 8, 1), blk, 0, stream, h2Hi, nullu, fcT_h, nullu,
                     fc_b, (float*)nullptr, fcbHi, nullu,
                     TT, 4 * CC, CC, 1, 0, nullf, nullf, (float*)nullptr, 1);
  // pr (split-K 4, single-pass bf16) + residual -> out
  hipLaunchKernelGGL(gemm_bf, dim3(12, 8, 4), blk, 0, stream, fcbHi, nullu, prT_h, nullu,
                     nullf, (float*)nullptr, nullu, nullu,
                     TT, CC, 4 * CC, 0, 0, nullf, nullf, gpart, 1);
  hipLaunchKernelGGL(gemm_combine_kernel, dim3((NTCE + 255) / 256), blk, 0, stream,
                     gpart, 4, TT, CC, pr_b, out,
                     nullu, nullu, 0, x2, nullf);
}

// Round 18
// 247.637 us; speedup vs baseline: 1.0085x; 1.0085x over previous
//
#include <hip/hip_runtime.h>
#include <hip/hip_bf16.h>
#include <math.h>

#define TT 512
#define CC 768
#define HH 12
#define DD 64
#define KKEEP 64
#define TOPG 128
#define NTCE (TT * CC)
#define NPAIR 36
#define PW (5 * CC)  // hoa plane width

typedef __attribute__((ext_vector_type(8))) short bf16x8;
typedef __attribute__((ext_vector_type(8))) unsigned short ushort8v;
typedef __attribute__((ext_vector_type(4))) float f32x4;
typedef unsigned long long u64;

// ---------------- helpers ----------------
__device__ __forceinline__ float block_sum(float v, float* red) {
#pragma unroll
  for (int off = 32; off; off >>= 1) v += __shfl_xor(v, off);
  __syncthreads();
  if ((threadIdx.x & 63) == 0) red[threadIdx.x >> 6] = v;
  __syncthreads();
  return red[0] + red[1] + red[2] + red[3];
}

__device__ __forceinline__ unsigned short f32_to_bf16_rne(float f) {
  unsigned u = __float_as_uint(f);
  unsigned r = (u + 0x7FFFu + ((u >> 16) & 1u)) >> 16;
  return (unsigned short)r;
}
__device__ __forceinline__ float bf16_to_f32(unsigned short h) {
  return __uint_as_float(((unsigned)h) << 16);
}
__device__ __forceinline__ void split2(float x, unsigned short& h, unsigned short& l) {
  h = f32_to_bf16_rne(x);
  l = f32_to_bf16_rne(x - bf16_to_f32(h));
}
__device__ __forceinline__ int swz(int row, int k) {
  return row * 64 + ((((k >> 3) ^ (row & 7))) << 3) + (k & 7);
}

// ---------------- weight split+transpose (all 10 weights, one dispatch) ----------------
struct WSplitArgs {
  const float* src[10];
  unsigned short* hi[10];
  unsigned short* lo[10];
  int K[10], N[10], tstart[10];
};

__global__ __launch_bounds__(256) void wsplitT_kernel(WSplitArgs a) {
  __shared__ float tile_[64][65];
  int t = blockIdx.x;
  int wsel = 0;
#pragma unroll
  for (int i = 1; i < 10; i++)
    if (t >= a.tstart[i]) wsel = i;
  int local = t - a.tstart[wsel];
  int K = a.K[wsel], N = a.N[wsel];
  int ntn = N >> 6;
  int bn = local % ntn, bk = local / ntn;
  int tid = threadIdx.x, r = tid >> 2, cq = tid & 3;
  const float* src = a.src[wsel] + (size_t)(bk * 64 + r) * N + bn * 64 + cq * 16;
#pragma unroll
  for (int f = 0; f < 4; f++) {
    float4 v = *(const float4*)(src + f * 4);
    tile_[r][cq * 16 + f * 4 + 0] = v.x;
    tile_[r][cq * 16 + f * 4 + 1] = v.y;
    tile_[r][cq * 16 + f * 4 + 2] = v.z;
    tile_[r][cq * 16 + f * 4 + 3] = v.w;
  }
  __syncthreads();
  size_t dst = (size_t)(bn * 64 + r) * K + bk * 64 + cq * 16;
  unsigned short hv[16], lv[16];
#pragma unroll
  for (int i = 0; i < 16; i++) split2(tile_[cq * 16 + i][r], hv[i], lv[i]);
  *(ushort8v*)&a.hi[wsel][dst] = *(const ushort8v*)&hv[0];
  *(ushort8v*)&a.hi[wsel][dst + 8] = *(const ushort8v*)&hv[8];
  *(ushort8v*)&a.lo[wsel][dst] = *(const ushort8v*)&lv[0];
  *(ushort8v*)&a.lo[wsel][dst + 8] = *(const ushort8v*)&lv[8];
}

// ---------------- layernorm (planes out) ----------------
__global__ void ln_bf_kernel(const float* __restrict__ x, const float* __restrict__ w,
                             const float* __restrict__ b,
                             unsigned short* __restrict__ ohi, unsigned short* __restrict__ olo) {
  int t = blockIdx.x, tid = threadIdx.x;
  __shared__ float red[4];
  float ls = 0.f;
  for (int c = tid; c < CC; c += 256) ls += x[t * CC + c];
  float mean = block_sum(ls, red) * (1.f / CC);
  float lv = 0.f;
  for (int c = tid; c < CC; c += 256) { float d = x[t * CC + c] - mean; lv += d * d; }
  float var = block_sum(lv, red) * (1.f / CC);
  float rs = rsqrtf(var + 1e-5f);
  for (int c = tid; c < CC; c += 256) {
    float val = (x[t * CC + c] - mean) * rs * w[c] + b[c];
    unsigned short hb, lb;
    split2(val, hb, lb);
    ohi[t * CC + c] = hb;
    olo[t * CC + c] = lb;
  }
}

// ---------------- fused split-K combine (+bias/mask/residual) + LN (+gate dot) -------
__global__ void combine_ln_kernel(
    const float* __restrict__ part, int ksplit, const float* __restrict__ bias,
    const float* __restrict__ res, const float* __restrict__ rowmask,
    float* __restrict__ xout, const float* __restrict__ lnw, const float* __restrict__ lnb,
    unsigned short* __restrict__ ohi, unsigned short* __restrict__ olo,
    const float* __restrict__ gw, const float* __restrict__ gb,
    float* __restrict__ gscore) {
  int t = blockIdx.x, tid = threadIdx.x;
  __shared__ float red[4];
  __shared__ float xrow[CC];
  float rm = rowmask ? rowmask[t] : 1.f;
  for (int c = tid; c < CC; c += 256) {
    float v = 0.f;
    for (int s = 0; s < ksplit; s++) v += part[(size_t)s * NTCE + (size_t)t * CC + c];
    if (bias) v += bias[c];
    v *= rm;
    v += res[(size_t)t * CC + c];
    xrow[c] = v;
    xout[(size_t)t * CC + c] = v;
  }
  __syncthreads();
  float ls = 0.f;
  for (int c = tid; c < CC; c += 256) ls += xrow[c];
  float mean = block_sum(ls, red) * (1.f / CC);
  float lv = 0.f;
  for (int c = tid; c < CC; c += 256) { float d = xrow[c] - mean; lv += d * d; }
  float var = block_sum(lv, red) * (1.f / CC);
  float rs = rsqrtf(var + 1e-5f);
  float gpart = 0.f;
  for (int c = tid; c < CC; c += 256) {
    float val = (xrow[c] - mean) * rs * lnw[c] + lnb[c];
    if (gscore) gpart += val * gw[c];
    unsigned short hb, lb;
    split2(val, hb, lb);
    ohi[(size_t)t * CC + c] = hb;
    if (olo) olo[(size_t)t * CC + c] = lb;
  }
  if (gscore) {
    float s = block_sum(gpart, red);
    if (tid == 0) gscore[t] = s + gb[0];
  }
}

// ---------------- split-bf16 MFMA GEMM (passes=3 exact, passes=1 fast bf16) ----------
__global__ __launch_bounds__(256) void gemm_bf(
    const unsigned short* __restrict__ Ah, const unsigned short* __restrict__ Al,
    const unsigned short* __restrict__ Bh, const unsigned short* __restrict__ Bl,
    const float* __restrict__ bias, float* __restrict__ Cf,
    unsigned short* __restrict__ Chi, unsigned short* __restrict__ Clo,
    int M, int N, int K, int act, int seg, const float* __restrict__ res,
    const float* __restrict__ rowmask, float* __restrict__ part, int passes) {
  __shared__ unsigned short AsH[64 * 64], AsL[64 * 64], BsH[64 * 64], BsL[64 * 64];
  int tid = threadIdx.x, lane = tid & 63, wave = tid >> 6;
  int wr = wave >> 1, wc = wave & 1, lr = lane & 15;
  int ksub = (lane >> 4) * 8;
  int n0 = blockIdx.x * 64, m0 = blockIdx.y * 64;
  int lrow = tid >> 2, lq = tid & 3;
  int kchunk = K / gridDim.z;
  int kstart = blockIdx.z * kchunk;

  f32x4 acc[2][2];
#pragma unroll
  for (int i = 0; i < 2; i++)
#pragma unroll
    for (int j = 0; j < 2; j++) acc[i][j] = (f32x4){0.f, 0.f, 0.f, 0.f};

  for (int k0 = kstart; k0 < kstart + kchunk; k0 += 64) {
    size_t aoff = (size_t)(m0 + lrow) * K + k0 + lq * 16;
    size_t boff = (size_t)(n0 + lrow) * K + k0 + lq * 16;
    int d0 = lrow * 64 + (((lq * 2) ^ (lrow & 7)) << 3);
    int d1 = lrow * 64 + (((lq * 2 + 1) ^ (lrow & 7)) << 3);
    *(ushort8v*)&AsH[d0] = *(const ushort8v*)&Ah[aoff];
    *(ushort8v*)&AsH[d1] = *(const ushort8v*)&Ah[aoff + 8];
    *(ushort8v*)&BsH[d0] = *(const ushort8v*)&Bh[boff];
    *(ushort8v*)&BsH[d1] = *(const ushort8v*)&Bh[boff + 8];
    if (passes == 3) {
      *(ushort8v*)&AsL[d0] = *(const ushort8v*)&Al[aoff];
      *(ushort8v*)&AsL[d1] = *(const ushort8v*)&Al[aoff + 8];
      *(ushort8v*)&BsL[d0] = *(const ushort8v*)&Bl[boff];
      *(ushort8v*)&BsL[d1] = *(const ushort8v*)&Bl[boff + 8];
    }
    __syncthreads();
#pragma unroll
    for (int kb = 0; kb < 2; kb++) {
      int kloc = kb * 32 + ksub;
      bf16x8 ah[2], al[2], bh[2], bl[2];
#pragma unroll
      for (int i = 0; i < 2; i++) {
        int m = wr * 32 + i * 16 + lr;
        int off = swz(m, kloc);
        ah[i] = *(const bf16x8*)&AsH[off];
        if (passes == 3) al[i] = *(const bf16x8*)&AsL[off];
      }
#pragma unroll
      for (int j = 0; j < 2; j++) {
        int n = wc * 32 + j * 16 + lr;
        int off = swz(n, kloc);
        bh[j] = *(const bf16x8*)&BsH[off];
        if (passes == 3) bl[j] = *(const bf16x8*)&BsL[off];
      }
#pragma unroll
      for (int i = 0; i < 2; i++)
#pragma unroll
        for (int j = 0; j < 2; j++) {
          acc[i][j] = __builtin_amdgcn_mfma_f32_16x16x32_bf16(ah[i], bh[j], acc[i][j], 0, 0, 0);
          if (passes == 3) {
            acc[i][j] = __builtin_amdgcn_mfma_f32_16x16x32_bf16(ah[i], bl[j], acc[i][j], 0, 0, 0);
            acc[i][j] = __builtin_amdgcn_mfma_f32_16x16x32_bf16(al[i], bh[j], acc[i][j], 0, 0, 0);
          }
        }
    }
    __syncthreads();
  }
  if (part) {
    float* pb = part + (size_t)blockIdx.z * M * N;
#pragma unroll
    for (int i = 0; i < 2; i++)
#pragma unroll
      for (int j = 0; j < 2; j++) {
        int col = n0 + wc * 32 + j * 16 + lr;
#pragma unroll
        for (int q = 0; q < 4; q++) {
          int row = m0 + wr * 32 + i * 16 + (lane >> 4) * 4 + q;
          pb[(size_t)row * N + col] = acc[i][j][q];
        }
      }
    return;
  }
#pragma unroll
  for (int i = 0; i < 2; i++)
#pragma unroll
    for (int j = 0; j < 2; j++) {
      int col = n0 + wc * 32 + j * 16 + lr;
      float bv = bias ? bias[col] : 0.f;
#pragma unroll
      for (int q = 0; q < 4; q++) {
        int row = m0 + wr * 32 + i * 16 + (lane >> 4) * 4 + q;
        float v = acc[i][j][q] + bv;
        if (act == 1) v = 0.5f * v * (1.f + erff(v * 0.70710678118654752f));
        if (rowmask) v *= rowmask[row];
        if (Cf) {
          size_t off = seg ? (size_t)(col / CC) * NTCE + (size_t)row * CC + (col % CC)
                           : (size_t)row * N + col;
          if (res) v += res[off];
          Cf[off] = v;
        }
        if (Chi) {
          size_t o2 = (size_t)row * N + col;
          unsigned short hb, lb;
          split2(v, hb, lb);
          Chi[o2] = hb;
          if (Clo) Clo[o2] = lb;
        }
      }
    }
}

// ---------------- split-K combine (bias/act/rowmask/res epilogue) ----------------
__global__ __launch_bounds__(256) void gemm_combine_kernel(
    const float* __restrict__ part, int ksplit, int M, int N,
    const float* __restrict__ bias, float* __restrict__ Cf,
    unsigned short* __restrict__ Chi, unsigned short* __restrict__ Clo,
    int act, const float* __restrict__ res, const float* __restrict__ rowmask) {
  int i = blockIdx.x * 256 + threadIdx.x;
  if (i >= M * N) return;
  int row = i / N, col = i - row * N;
  float v = 0.f;
  for (int s = 0; s < ksplit; s++) v += part[(size_t)s * M * N + i];
  if (bias) v += bias[col];
  if (act == 1) v = 0.5f * v * (1.f + erff(v * 0.70710678118654752f));
  if (rowmask) v *= rowmask[row];
  if (Cf) {
    if (res) v += res[i];
    Cf[i] = v;
  }
  if (Chi) {
    unsigned short hb, lb;
    split2(v, hb, lb);
    Chi[i] = hb;
    if (Clo) Clo[i] = lb;
  }
}

// ---------------- SDPA split-K from qkv bf16 planes: per (h, tile-pair) partial ------
__global__ __launch_bounds__(256) void sdpa_part_kernel(
    const unsigned short* __restrict__ qkvh, const unsigned short* __restrict__ qkvl,
    float* __restrict__ oPart, float* __restrict__ mPart, float* __restrict__ lPart) {
  int h = blockIdx.x;
  int p = blockIdx.y;  // 0..35 lower-triangle pair
  int bt = 0, base = 0;
  while (p >= base + bt + 1) { base += bt + 1; bt++; }
  int st = p - base;
  int t0 = bt * 64, s0 = st * 64;
  int tid = threadIdx.x, lane = tid & 63, w = tid >> 6;
  int lr = lane & 15, ksub = (lane >> 4) * 8;
  const int hDD = h * DD;

  __shared__ unsigned short qHi[64 * 64], qLo[64 * 64];
  __shared__ unsigned short kHi[64 * 64], kLo[64 * 64];
  __shared__ unsigned short bufP[64 * 64], bufV[64 * 64];

  int lrow = tid >> 2, lq = tid & 3;
  {
    size_t qoff = (size_t)(t0 + lrow) * (3 * CC) + hDD + lq * 16;
    size_t koff = (size_t)(s0 + lrow) * (3 * CC) + CC + hDD + lq * 16;
    int d0 = lrow * 64 + (((lq * 2) ^ (lrow & 7)) << 3);
    int d1 = lrow * 64 + (((lq * 2 + 1) ^ (lrow & 7)) << 3);
    *(ushort8v*)&qHi[d0] = *(const ushort8v*)&qkvh[qoff];
    *(ushort8v*)&qHi[d1] = *(const ushort8v*)&qkvh[qoff + 8];
    *(ushort8v*)&qLo[d0] = *(const ushort8v*)&qkvl[qoff];
    *(ushort8v*)&qLo[d1] = *(const ushort8v*)&qkvl[qoff + 8];
    *(ushort8v*)&kHi[d0] = *(const ushort8v*)&qkvh[koff];
    *(ushort8v*)&kHi[d1] = *(const ushort8v*)&qkvh[koff + 8];
    *(ushort8v*)&kLo[d0] = *(const ushort8v*)&qkvl[koff];
    *(ushort8v*)&kLo[d1] = *(const ushort8v*)&qkvl[koff + 8];
  }
  // V stage: direct hi copy, diagonal rotation avoids conflicts
#pragma unroll
  for (int r = 0; r < 16; r++) {
    int sl = w * 16 + ((r + (lane >> 3)) & 15);
    bufV[swz(lane, sl)] = qkvh[(size_t)(s0 + sl) * (3 * CC) + 2 * CC + hDD + lane];
  }
  __syncthreads();
  // S = Q K^T
  f32x4 acc[4];
#pragma unroll
  for (int nt = 0; nt < 4; nt++) acc[nt] = (f32x4){0.f, 0.f, 0.f, 0.f};
  {
    bf16x8 ah[2], al[2];
#pragma unroll
    for (int kb = 0; kb < 2; kb++) {
      int off = swz(w * 16 + lr, kb * 32 + ksub);
      ah[kb] = *(const bf16x8*)&qHi[off];
      al[kb] = *(const bf16x8*)&qLo[off];
    }
#pragma unroll
    for (int nt = 0; nt < 4; nt++)
#pragma unroll
      for (int kb = 0; kb < 2; kb++) {
        int off = swz(nt * 16 + lr, kb * 32 + ksub);
        bf16x8 bh = *(const bf16x8*)&kHi[off];
        bf16x8 bl = *(const bf16x8*)&kLo[off];
        acc[nt] = __builtin_amdgcn_mfma_f32_16x16x32_bf16(ah[kb], bh, acc[nt], 0, 0, 0);
        acc[nt] = __builtin_amdgcn_mfma_f32_16x16x32_bf16(ah[kb], bl, acc[nt], 0, 0, 0);
        acc[nt] = __builtin_amdgcn_mfma_f32_16x16x32_bf16(al[kb], bh, acc[nt], 0, 0, 0);
      }
  }
  // per-row tile softmax numerator (exp relative to tile max)
  int pbase = (h * NPAIR + p) * 64;
#pragma unroll
  for (int q = 0; q < 4; q++) {
    int rloc = w * 16 + (lane >> 4) * 4 + q;
    float tm = -INFINITY;
#pragma unroll
    for (int nt = 0; nt < 4; nt++) {
      float v = acc[nt][q] * 0.125f;
      if (st == bt && nt * 16 + lr > rloc) v = -INFINITY;
      acc[nt][q] = v;
      tm = fmaxf(tm, v);
    }
#pragma unroll
    for (int off = 1; off < 16; off <<= 1) tm = fmaxf(tm, __shfl_xor(tm, off));
    float ps = 0.f;
#pragma unroll
    for (int nt = 0; nt < 4; nt++) {
      float e = __expf(acc[nt][q] - tm);
      acc[nt][q] = e;
      ps += e;
    }
#pragma unroll
    for (int off = 1; off < 16; off <<= 1) ps += __shfl_xor(ps, off);
    if (lr == 0) {
      mPart[pbase + rloc] = tm;
      lPart[pbase + rloc] = ps;
    }
  }
  // P -> LDS bf16
#pragma unroll
  for (int nt = 0; nt < 4; nt++)
#pragma unroll
    for (int q = 0; q < 4; q++) {
      int row = w * 16 + (lane >> 4) * 4 + q;
      int col = nt * 16 + lr;
      bufP[swz(row, col)] = f32_to_bf16_rne(acc[nt][q]);
    }
  __syncthreads();
  // O_part = P V^T
  f32x4 o[4];
#pragma unroll
  for (int nt = 0; nt < 4; nt++) o[nt] = (f32x4){0.f, 0.f, 0.f, 0.f};
  {
    bf16x8 pf[2];
#pragma unroll
    for (int kb = 0; kb < 2; kb++)
      pf[kb] = *(const bf16x8*)&bufP[swz(w * 16 + lr, kb * 32 + ksub)];
#pragma unroll
    for (int nt = 0; nt < 4; nt++)
#pragma unroll
      for (int kb = 0; kb < 2; kb++) {
        bf16x8 bv = *(const bf16x8*)&bufV[swz(nt * 16 + lr, kb * 32 + ksub)];
        o[nt] = __builtin_amdgcn_mfma_f32_16x16x32_bf16(pf[kb], bv, o[nt], 0, 0, 0);
      }
  }
  float* obase = oPart + ((size_t)(h * NPAIR + p) << 12);
#pragma unroll
  for (int nt = 0; nt < 4; nt++)
#pragma unroll
    for (int q = 0; q < 4; q++) {
      int row = w * 16 + (lane >> 4) * 4 + q;
      int col = nt * 16 + lr;
      obase[row * 64 + col] = o[nt][q];
    }
}

// ---------------- SDPA combine: one thread per (t-row, d) element ----------------
__global__ __launch_bounds__(256) void sdpa_combine_kernel(
    const float* __restrict__ oPart, const float* __restrict__ mPart,
    const float* __restrict__ lPart,
    unsigned short* __restrict__ yhi, unsigned short* __restrict__ ylo) {
  int h = blockIdx.x, bt = blockIdx.y;
  int base = bt * (bt + 1) / 2;
  int n = bt + 1;
  int tid = threadIdx.x;
  int d = tid & 63;
  int r = blockIdx.z * 4 + (tid >> 6);  // 4 rows per block
  int t0 = bt * 64;
  float mg = -INFINITY;
  for (int s = 0; s < n; s++)
    mg = fmaxf(mg, mPart[(h * NPAIR + base + s) * 64 + r]);
  float lg = 0.f, oacc = 0.f;
  for (int s = 0; s < n; s++) {
    int pi = h * NPAIR + base + s;
    float sc = __expf(mPart[pi * 64 + r] - mg);
    lg += sc * lPart[pi * 64 + r];
    oacc += sc * oPart[((size_t)pi << 12) + r * 64 + d];
  }
  float v = oacc / lg;
  unsigned short hb, lb;
  split2(v, hb, lb);
  yhi[(size_t)(t0 + r) * CC + h * DD + d] = hb;
  ylo[(size_t)(t0 + r) * CC + h * DD + d] = lb;
}

// ---------------- HOA score GEMM from bf16 planes [T][5CC] ----------------
__global__ __launch_bounds__(256) void score_gemm_kernel(
    const unsigned short* __restrict__ ph, const unsigned short* __restrict__ pl,
    float* __restrict__ scores) {
  if (blockIdx.x > blockIdx.y) return;
  int bh = blockIdx.z;
  int br = bh >= HH ? 1 : 0;
  int h = bh - br * HH;
  int s0 = blockIdx.x * 64, t0 = blockIdx.y * 64;
  int hDD = h * DD;
  int kcol = (1 + br) * CC + hDD;
  __shared__ unsigned short AsH[64 * 64], AsL[64 * 64], BsH[64 * 64], BsL[64 * 64];
  int tid = threadIdx.x, lane = tid & 63, wave = tid >> 6;
  int wr = wave >> 1, wc = wave & 1, lr = lane & 15;
  int ksub = (lane >> 4) * 8;
  int lrow = tid >> 2, lq = tid & 3;
  {
    size_t aoff = (size_t)(t0 + lrow) * PW + hDD + lq * 16;
    size_t boff = (size_t)(s0 + lrow) * PW + kcol + lq * 16;
    int d0 = lrow * 64 + (((lq * 2) ^ (lrow & 7)) << 3);
    int d1 = lrow * 64 + (((lq * 2 + 1) ^ (lrow & 7)) << 3);
    *(ushort8v*)&AsH[d0] = *(const ushort8v*)&ph[aoff];
    *(ushort8v*)&AsH[d1] = *(const ushort8v*)&ph[aoff + 8];
    *(ushort8v*)&AsL[d0] = *(const ushort8v*)&pl[aoff];
    *(ushort8v*)&AsL[d1] = *(const ushort8v*)&pl[aoff + 8];
    *(ushort8v*)&BsH[d0] = *(const ushort8v*)&ph[boff];
    *(ushort8v*)&BsH[d1] = *(const ushort8v*)&ph[boff + 8];
    *(ushort8v*)&BsL[d0] = *(const ushort8v*)&pl[boff];
    *(ushort8v*)&BsL[d1] = *(const ushort8v*)&pl[boff + 8];
  }
  __syncthreads();
  f32x4 acc[2][2];
#pragma unroll
  for (int i = 0; i < 2; i++)
#pragma unroll
    for (int j = 0; j < 2; j++) acc[i][j] = (f32x4){0.f, 0.f, 0.f, 0.f};
#pragma unroll
  for (int kb = 0; kb < 2; kb++) {
    int kloc = kb * 32 + ksub;
    bf16x8 ah[2], al[2], bh_[2], bl[2];
#pragma unroll
    for (int i = 0; i < 2; i++) {
      int m = wr * 32 + i * 16 + lr;
      int off = swz(m, kloc);
      ah[i] = *(const bf16x8*)&AsH[off];
      al[i] = *(const bf16x8*)&AsL[off];
    }
#pragma unroll
    for (int j = 0; j < 2; j++) {
      int n = wc * 32 + j * 16 + lr;
      int off = swz(n, kloc);
      bh_[j] = *(const bf16x8*)&BsH[off];
      bl[j] = *(const bf16x8*)&BsL[off];
    }
#pragma unroll
    for (int i = 0; i < 2; i++)
#pragma unroll
      for (int j = 0; j < 2; j++) {
        acc[i][j] = __builtin_amdgcn_mfma_f32_16x16x32_bf16(ah[i], bh_[j], acc[i][j], 0, 0, 0);
        acc[i][j] = __builtin_amdgcn_mfma_f32_16x16x32_bf16(ah[i], bl[j], acc[i][j], 0, 0, 0);
        acc[i][j] = __builtin_amdgcn_mfma_f32_16x16x32_bf16(al[i], bh_[j], acc[i][j], 0, 0, 0);
      }
  }
#pragma unroll
  for (int i = 0; i < 2; i++)
#pragma unroll
    for (int j = 0; j < 2; j++)
#pragma unroll
      for (int q = 0; q < 4; q++) {
        int tt = t0 + wr * 32 + i * 16 + (lane >> 4) * 4 + q;
        int ss = s0 + wc * 32 + j * 16 + lr;
        scores[((size_t)bh * TT + tt) * TT + ss] = acc[i][j][q];
      }
}

// ---------------- low-LDS shuffle primitives (DPP / ds_swizzle) ----------
template<int CTRL>
__device__ __forceinline__ u64 dpp64(u64 x) {
  unsigned lo = (unsigned)__builtin_amdgcn_update_dpp(
      (int)(unsigned)x, (int)(unsigned)x, CTRL, 0xF, 0xF, true);
  unsigned hi = (unsigned)__builtin_amdgcn_update_dpp(
      (int)(unsigned)(x >> 32), (int)(unsigned)(x >> 32), CTRL, 0xF, 0xF, true);
  return ((u64)hi << 32) | lo;
}
template<int MASK>
__device__ __forceinline__ u64 swz64(u64 x) {
  unsigned lo = (unsigned)__builtin_amdgcn_ds_swizzle((int)(unsigned)x, (MASK << 10) | 0x1F);
  unsigned hi = (unsigned)__builtin_amdgcn_ds_swizzle((int)(unsigned)(x >> 32), (MASK << 10) | 0x1F);
  return ((u64)hi << 32) | lo;
}
__device__ __forceinline__ u64 cas_dir(u64 x, u64 y, bool low) {
  bool take_y = low ? (y > x) : (y < x);
  return take_y ? y : x;
}
__device__ __forceinline__ u64 sort64m(u64 x, int lane) {
  x = cas_dir(x, dpp64<0xB1>(x), (lane & 1) == 0);
  x = cas_dir(x, dpp64<0x1B>(x), (lane & 2) == 0);
  x = cas_dir(x, dpp64<0xB1>(x), (lane & 1) == 0);
  x = cas_dir(x, dpp64<0x141>(x), (lane & 4) == 0);
  x = cas_dir(x, dpp64<0x4E>(x), (lane & 2) == 0);
  x = cas_dir(x, dpp64<0xB1>(x), (lane & 1) == 0);
  x = cas_dir(x, dpp64<0x140>(x), (lane & 8) == 0);
  x = cas_dir(x, swz64<4>(x), (lane & 4) == 0);
  x = cas_dir(x, dpp64<0x4E>(x), (lane & 2) == 0);
  x = cas_dir(x, dpp64<0xB1>(x), (lane & 1) == 0);
  x = cas_dir(x, swz64<31>(x), (lane & 16) == 0);
  x = cas_dir(x, swz64<8>(x), (lane & 8) == 0);
  x = cas_dir(x, swz64<4>(x), (lane & 4) == 0);
  x = cas_dir(x, dpp64<0x4E>(x), (lane & 2) == 0);
  x = cas_dir(x, dpp64<0xB1>(x), (lane & 1) == 0);
  x = cas_dir(x, __shfl_xor(x, 63), (lane & 32) == 0);
  x = cas_dir(x, swz64<16>(x), (lane & 16) == 0);
  x = cas_dir(x, swz64<8>(x), (lane & 8) == 0);
  x = cas_dir(x, swz64<4>(x), (lane & 4) == 0);
  x = cas_dir(x, dpp64<0x4E>(x), (lane & 2) == 0);
  x = cas_dir(x, dpp64<0xB1>(x), (lane & 1) == 0);
  return x;
}
__device__ __forceinline__ u64 merge64m(u64 x, int lane) {
  x = cas_dir(x, __shfl_xor(x, 32), (lane & 32) == 0);
  x = cas_dir(x, swz64<16>(x), (lane & 16) == 0);
  x = cas_dir(x, swz64<8>(x), (lane & 8) == 0);
  x = cas_dir(x, swz64<4>(x), (lane & 4) == 0);
  x = cas_dir(x, dpp64<0x4E>(x), (lane & 2) == 0);
  x = cas_dir(x, dpp64<0xB1>(x), (lane & 1) == 0);
  return x;
}
__device__ __forceinline__ u64 merge2m(u64 a, u64 b, int lane) {
  u64 rev = __shfl_xor(b, 63);
  u64 run = a > rev ? a : rev;
  return merge64m(run, lane);
}
__device__ __forceinline__ u64 make_key(float v, int s, int t) {
  unsigned sv = 0u;
  if (s <= t) {
    unsigned u = __float_as_uint(v);
    sv = (u & 0x80000000u) ? ~u : (u | 0x80000000u);
  }
  return ((u64)sv << 32) | (unsigned)(~s);
}

// ---------------- wave top-64 selection: chunk-skip + tree merge (1 row/wave) --------
__global__ __launch_bounds__(256) void topk_select_kernel(
    const float* __restrict__ scores, int* __restrict__ idx1, int* __restrict__ idx2) {
  int tid = threadIdx.x, lane = tid & 63, w = tid >> 6;
  int row = blockIdx.x * 4 + w;
  int br = row >= (HH * TT) ? 1 : 0;
  int rem = row - br * (HH * TT);
  int h = rem >> 9, t = rem & (TT - 1);
  const float* sr = scores + ((size_t)(br * HH + h) * TT + t) * TT;
  int nc = (t >> 6) + 1;
  u64 c[8];
#pragma unroll
  for (int e = 0; e < 8; e++) {
    if (e < nc)
      c[e] = sort64m(make_key(sr[e * 64 + lane], e * 64 + lane, t), lane);
    else
      c[e] = (u64)(unsigned)(~(e * 64 + lane));
  }
  u64 l10 = (t >= 64)  ? merge2m(c[0], c[1], lane) : c[0];
  u64 l11 = (t >= 192) ? merge2m(c[2], c[3], lane) : c[2];
  u64 l12 = (t >= 320) ? merge2m(c[4], c[5], lane) : c[4];
  u64 l13 = (t >= 448) ? merge2m(c[6], c[7], lane) : c[6];
  u64 l20 = (t >= 128) ? merge2m(l10, l11, lane) : l10;
  u64 l21 = (t >= 384) ? merge2m(l12, l13, lane) : l12;
  u64 res = (t >= 256) ? merge2m(l20, l21, lane) : l20;
  unsigned myidx = ~(unsigned)res;
  unsigned outv = __shfl(myidx, min(lane, t));
  int* idxout = (br ? idx2 : idx1) + ((size_t)h * TT + t) * KKEEP;
  idxout[lane] = (int)outv;
}

// ---------------- register bitonic sort of 512 u64 keys across one wave (gate) -------
__device__ __forceinline__ u64 cas_u64(u64 x, int j, bool dirmax, int lane) {
  u64 y = __shfl_xor(x, j);
  bool lower = (lane & j) == 0;
  bool keepmax = (dirmax == lower);
  return (keepmax ? (y > x) : (y < x)) ? y : x;
}
__device__ __forceinline__ void sort512(u64* key, int lane) {
#pragma unroll
  for (int k = 2; k <= 512; k <<= 1) {
#pragma unroll
    for (int j = k >> 1; j > 0; j >>= 1) {
      if (j < 64) {
        bool lower = (lane & j) == 0;
#pragma unroll
        for (int e = 0; e < 8; e++) {
          bool desc = ((((e << 6) | lane) & k) == 0);
          u64 part = __shfl_xor(key[e], j);
          bool wantmax = (desc == lower);
          key[e] = (wantmax ? (part > key[e]) : (part < key[e])) ? part : key[e];
        }
      } else {
        int m = j >> 6;
#pragma unroll
        for (int e = 0; e < 8; e++) {
          if ((e & m) == 0) {
            int e2 = e | m;
            bool desc = ((((e << 6) | lane) & k) == 0);
            u64 a = key[e], b = key[e2];
            u64 mx = a > b ? a : b;
            u64 mn = a > b ? b : a;
            key[e] = desc ? mx : mn;
            key[e2] = desc ? mn : mx;
          }
        }
      }
    }
  }
}

// ---------------- HOA core: MFMA from bf16 planes (vectorized staging) ----------
__global__ __launch_bounds__(256) void hoa_core_kernel(
    const unsigned short* __restrict__ ph, const unsigned short* __restrict__ pl,
    const int* __restrict__ idx1, const int* __restrict__ idx2,
    unsigned short* __restrict__ hcohi) {
  int h = blockIdx.x, t = blockIdx.y, tid = threadIdx.x;
  int lane = tid & 63, w = tid >> 6;
  int lr = lane & 15;
  int ksub = (lane >> 4) * 8;
  const int hDD = h * DD;

  __shared__ unsigned short bufA[64 * 64];
  __shared__ unsigned short bufB[64 * 64];
  __shared__ unsigned short v1s[64 * 68];
  __shared__ float red[4 * 64];
  __shared__ int i1s[64], i2s[64];

  if (tid < 64) {
    i1s[tid] = idx1[(h * TT + t) * KKEEP + tid] * PW + CC + hDD;      // K1 plane offset
    i2s[tid] = idx2[(h * TT + t) * KKEEP + tid] * PW + 2 * CC + hDD;  // K2 plane offset
  }
  __syncthreads();

  // vectorized staging: lane covers 2 adjacent k-elements; 32 lanes/row, 2 rows/iter
  int half = lane >> 5;
  int c2 = (lane & 31) * 2;
  size_t qbase = (size_t)t * PW + hDD;
  float qf0 = bf16_to_f32(ph[qbase + c2]) + bf16_to_f32(pl[qbase + c2]);
  float qf1 = bf16_to_f32(ph[qbase + c2 + 1]) + bf16_to_f32(pl[qbase + c2 + 1]);
#pragma unroll
  for (int r = 0; r < 8; r++) {
    int j = w * 16 + r * 2 + half;
    unsigned k1p = *(const unsigned*)&ph[i1s[j] + c2];
    unsigned k2p = *(const unsigned*)&ph[i2s[j] + c2];
    unsigned v1p = *(const unsigned*)&ph[i1s[j] + 2 * CC + c2];
    unsigned short a0 = f32_to_bf16_rne(bf16_to_f32((unsigned short)(k1p & 0xFFFFu)) * qf0);
    unsigned short a1 = f32_to_bf16_rne(bf16_to_f32((unsigned short)(k1p >> 16)) * qf1);
    int off = swz(j, c2);
    *(unsigned*)&bufA[off] = (unsigned)a0 | ((unsigned)a1 << 16);
    *(unsigned*)&bufB[off] = k2p;
    *(unsigned*)&v1s[j * 68 + c2] = v1p;
  }
  __syncthreads();

  f32x4 acc[4];
#pragma unroll
  for (int nt = 0; nt < 4; nt++) acc[nt] = (f32x4){0.f, 0.f, 0.f, 0.f};
  {
    bf16x8 af[2];
#pragma unroll
    for (int kb = 0; kb < 2; kb++)
      af[kb] = *(const bf16x8*)&bufA[swz(w * 16 + lr, kb * 32 + ksub)];
#pragma unroll
    for (int nt = 0; nt < 4; nt++)
#pragma unroll
      for (int kb = 0; kb < 2; kb++) {
        bf16x8 bf = *(const bf16x8*)&bufB[swz(nt * 16 + lr, kb * 32 + ksub)];
        acc[nt] = __builtin_amdgcn_mfma_f32_16x16x32_bf16(af[kb], bf, acc[nt], 0, 0, 0);
      }
  }
#pragma unroll
  for (int q = 0; q < 4; q++) {
    float m = -INFINITY;
#pragma unroll
    for (int nt = 0; nt < 4; nt++) {
      acc[nt][q] *= 0.125f;
      m = fmaxf(m, acc[nt][q]);
    }
#pragma unroll
    for (int off = 1; off < 16; off <<= 1) m = fmaxf(m, __shfl_xor(m, off));
    float s = 0.f;
#pragma unroll
    for (int nt = 0; nt < 4; nt++) {
      float e = __expf(acc[nt][q] - m);
      acc[nt][q] = e;
      s += e;
    }
#pragma unroll
    for (int off = 1; off < 16; off <<= 1) s += __shfl_xor(s, off);
    float inv = 1.f / s;
#pragma unroll
    for (int nt = 0; nt < 4; nt++) acc[nt][q] *= inv;
  }
  __syncthreads();

#pragma unroll
  for (int nt = 0; nt < 4; nt++)
#pragma unroll
    for (int q = 0; q < 4; q++) {
      int row = w * 16 + (lane >> 4) * 4 + q;
      int col = nt * 16 + lr;
      bufA[swz(row, col)] = f32_to_bf16_rne(acc[nt][q]);
    }
  // V2 transpose gather: even-pair diagonal rotation, u32 writes
#pragma unroll
  for (int r = 0; r < 8; r++) {
    int kk = w * 16 + ((r * 2 + ((lane >> 3) * 2)) & 15);
    unsigned short b0 = ph[i2s[kk] + 2 * CC + lane];
    unsigned short b1 = ph[i2s[kk + 1] + 2 * CC + lane];
    int off = swz(lane, kk);
    *(unsigned*)&bufB[off] = (unsigned)b0 | ((unsigned)b1 << 16);
  }
  __syncthreads();

  f32x4 acc2[4];
#pragma unroll
  for (int nt = 0; nt < 4; nt++) acc2[nt] = (f32x4){0.f, 0.f, 0.f, 0.f};
  {
    bf16x8 af[2];
#pragma unroll
    for (int kb = 0; kb < 2; kb++)
      af[kb] = *(const bf16x8*)&bufA[swz(w * 16 + lr, kb * 32 + ksub)];
#pragma unroll
    for (int nt = 0; nt < 4; nt++)
#pragma unroll
      for (int kb = 0; kb < 2; kb++) {
        bf16x8 bf = *(const bf16x8*)&bufB[swz(nt * 16 + lr, kb * 32 + ksub)];
        acc2[nt] = __builtin_amdgcn_mfma_f32_16x16x32_bf16(af[kb], bf, acc2[nt], 0, 0, 0);
      }
  }
#pragma unroll
  for (int nt = 0; nt < 4; nt++) {
    float p = 0.f;
#pragma unroll
    for (int q = 0; q < 4; q++) {
      int row = w * 16 + (lane >> 4) * 4 + q;
      int col = lr + 16 * nt;
      p += acc2[nt][q] * bf16_to_f32(v1s[row * 68 + col]);
    }
    p += __shfl_xor(p, 16);
    p += __shfl_xor(p, 32);
    if (lane < 16) red[w * 64 + 16 * nt + lr] = p;
  }
  __syncthreads();
  if (tid < 64) {
    float o = red[tid] + red[64 + tid] + red[128 + tid] + red[192 + tid];
    hcohi[t * CC + hDD + tid] = f32_to_bf16_rne(o);
  }
}

// ---------------- gate mask ----------------
__global__ void gate_mask_kernel(const float* __restrict__ scores, float* __restrict__ mask) {
  int lane = threadIdx.x;  // 64 threads, one wave
  u64 key[8];
#pragma unroll
  for (int e = 0; e < 8; e++) {
    int s = e * 64 + lane;
    unsigned uu = __float_as_uint(scores[s]);
    unsigned sv = (uu & 0x80000000u) ? ~uu : (uu | 0x80000000u);
    key[e] = ((u64)sv << 32) | (unsigned)(~s);
    mask[s] = 0.f;
  }
  __asm__ volatile("s_waitcnt vmcnt(0)" ::: "memory");
  sort512(key, lane);
#pragma unroll
  for (int e = 0; e < 2; e++) mask[(int)(~(unsigned)key[e])] = 1.f;
}

// ---------------- launcher ----------------
extern "C" void kernel_launch(void* const* d_in, const int* in_sizes, int n_in,
                              void* d_out, int out_size, void* d_ws, size_t ws_size,
                              hipStream_t stream) {
  const float* x      = (const float*)d_in[0];
  const float* ln1_w  = (const float*)d_in[1];
  const float* ln1_b  = (const float*)d_in[2];
  const float* qkv_w  = (const float*)d_in[3];
  const float* qkv_b  = (const float*)d_in[4];
  const float* atto_w = (const float*)d_in[5];
  const float* atto_b = (const float*)d_in[6];
  const float* lnh_w  = (const float*)d_in[7];
  const float* lnh_b  = (const float*)d_in[8];
  const float* hq_w   = (const float*)d_in[9];
  const float* hk1_w  = (const float*)d_in[10];
  const float* hk2_w  = (const float*)d_in[11];
  const float* hv1_w  = (const float*)d_in[12];
  const float* hv2_w  = (const float*)d_in[13];
  const float* ho_w   = (const float*)d_in[14];
  const float* gate_w = (const float*)d_in[15];
  const float* gate_b = (const float*)d_in[16];
  const float* ln2_w  = (const float*)d_in[17];
  const float* ln2_b  = (const float*)d_in[18];
  const float* fc_w   = (const float*)d_in[19];
  const float* fc_b   = (const float*)d_in[20];
  const float* pr_w   = (const float*)d_in[21];
  const float* pr_b   = (const float*)d_in[22];
  float* out = (float*)d_out;

  // workspace carve-up
  char* cur = (char*)d_ws;
  auto alloc = [&](size_t bytes) {
    char* p = cur;
    cur += (bytes + 255) & ~(size_t)255;
    return p;
  };
  float* x1   = (float*)alloc((size_t)NTCE * 4);
  float* x2   = (float*)alloc((size_t)NTCE * 4);
  float* scores = (float*)alloc(TT * 4);
  float* maskb  = (float*)alloc(TT * 4);
  int* idx1 = (int*)alloc((size_t)HH * TT * KKEEP * 4);
  int* idx2 = (int*)alloc((size_t)HH * TT * KKEEP * 4);
  float* hscores = (float*)alloc((size_t)2 * HH * TT * TT * 4);  // 25 MB
  float* oPart = (float*)alloc((size_t)HH * NPAIR * 64 * 64 * 4);  // 7.1 MB
  float* mPart = (float*)alloc((size_t)HH * NPAIR * 64 * 4);
  float* lPart = (float*)alloc((size_t)HH * NPAIR * 64 * 4);
  float* gpart = (float*)alloc((size_t)2 * TT * 4 * CC * 4);  // split-K partials
  // activation planes
  unsigned short* hHi    = (unsigned short*)alloc((size_t)NTCE * 2);
  unsigned short* hLo    = (unsigned short*)alloc((size_t)NTCE * 2);
  unsigned short* qkvHi  = (unsigned short*)alloc((size_t)3 * NTCE * 2);
  unsigned short* qkvLo  = (unsigned short*)alloc((size_t)3 * NTCE * 2);
  unsigned short* yHi    = (unsigned short*)alloc((size_t)NTCE * 2);
  unsigned short* yLo    = (unsigned short*)alloc((size_t)NTCE * 2);
  unsigned short* hoinHi = (unsigned short*)alloc((size_t)NTCE * 2);
  unsigned short* hoinLo = (unsigned short*)alloc((size_t)NTCE * 2);
  unsigned short* hoaPh  = (unsigned short*)alloc((size_t)TT * PW * 2);  // [T][5CC] hi
  unsigned short* hoaPl  = (unsigned short*)alloc((size_t)TT * PW * 2);  // [T][5CC] lo
  unsigned short* h2Hi   = (unsigned short*)alloc((size_t)NTCE * 2);
  unsigned short* hcoHi  = (unsigned short*)alloc((size_t)NTCE * 2);
  unsigned short* fcbHi  = (unsigned short*)alloc((size_t)4 * NTCE * 2);
  // weight planes (transposed [N][K])
  const size_t WSQ = (size_t)CC * CC;
  unsigned short* qkvT_h = (unsigned short*)alloc((size_t)CC * 3 * CC * 2);
  unsigned short* qkvT_l = (unsigned short*)alloc((size_t)CC * 3 * CC * 2);
  unsigned short* attoT_h = (unsigned short*)alloc(WSQ * 2);
  unsigned short* attoT_l = (unsigned short*)alloc(WSQ * 2);
  unsigned short* hoaT_h = (unsigned short*)alloc(5 * WSQ * 2);
  unsigned short* hoaT_l = (unsigned short*)alloc(5 * WSQ * 2);
  unsigned short* hoT_h = (unsigned short*)alloc(WSQ * 2);
  unsigned short* hoT_l = (unsigned short*)alloc(WSQ * 2);
  unsigned short* fcT_h = (unsigned short*)alloc((size_t)CC * 4 * CC * 2);
  unsigned short* fcT_l = (unsigned short*)alloc((size_t)CC * 4 * CC * 2);
  unsigned short* prT_h = (unsigned short*)alloc((size_t)CC * 4 * CC * 2);
  unsigned short* prT_l = (unsigned short*)alloc((size_t)CC * 4 * CC * 2);

  // weight split jobs
  WSplitArgs wa;
  int tcur = 0;
  auto addw = [&](int i, const float* s, unsigned short* hi, unsigned short* lo, int K, int N) {
    wa.src[i] = s; wa.hi[i] = hi; wa.lo[i] = lo;
    wa.K[i] = K; wa.N[i] = N; wa.tstart[i] = tcur;
    tcur += (N / 64) * (K / 64);
  };
  addw(0, qkv_w, qkvT_h, qkvT_l, CC, 3 * CC);
  addw(1, atto_w, attoT_h, attoT_l, CC, CC);
  addw(2, hq_w,  hoaT_h + 0 * WSQ, hoaT_l + 0 * WSQ, CC, CC);
  addw(3, hk1_w, hoaT_h + 1 * WSQ, hoaT_l + 1 * WSQ, CC, CC);
  addw(4, hk2_w, hoaT_h + 2 * WSQ, hoaT_l + 2 * WSQ, CC, CC);
  addw(5, hv1_w, hoaT_h + 3 * WSQ, hoaT_l + 3 * WSQ, CC, CC);
  addw(6, hv2_w, hoaT_h + 4 * WSQ, hoaT_l + 4 * WSQ, CC, CC);
  addw(7, ho_w, hoT_h, hoT_l, CC, CC);
  addw(8, fc_w, fcT_h, fcT_l, CC, 4 * CC);
  addw(9, pr_w, prT_h, prT_l, 4 * CC, CC);

  dim3 blk(256);
  const float* nullf = nullptr;
  unsigned short* nullu = nullptr;

  hipLaunchKernelGGL(wsplitT_kernel, dim3(tcur), blk, 0, stream, wa);
  // LN1 -> h planes
  hipLaunchKernelGGL(ln_bf_kernel, dim3(TT), blk, 0, stream, x, ln1_w, ln1_b, hHi, hLo);
  // QKV (3-pass exact) -> bf16 planes directly
  hipLaunchKernelGGL(gemm_bf, dim3(36, 8, 1), blk, 0, stream, hHi, hLo, qkvT_h, qkvT_l,
                     qkv_b, (float*)nullptr, qkvHi, qkvLo,
                     TT, 3 * CC, CC, 0, 0, nullf, nullf, (float*)nullptr, 3);
  // SDPA split-K (from planes)
  hipLaunchKernelGGL(sdpa_part_kernel, dim3(HH, NPAIR), blk, 0, stream,
                     qkvHi, qkvLo, oPart, mPart, lPart);
  hipLaunchKernelGGL(sdpa_combine_kernel, dim3(HH, 8, 16), blk, 0, stream,
                     oPart, mPart, lPart, yHi, yLo);
  // atto (split-K 2, 3-pass)
  hipLaunchKernelGGL(gemm_bf, dim3(12, 8, 2), blk, 0, stream, yHi, yLo, attoT_h, attoT_l,
                     nullf, (float*)nullptr, nullu, nullu,
                     TT, CC, CC, 0, 0, nullf, nullf, gpart, 3);
  // fused: atto-combine (+bias, +x residual) -> x1, then LNh (+gate dot) -> hoin planes
  hipLaunchKernelGGL(combine_ln_kernel, dim3(TT), blk, 0, stream,
                     gpart, 2, atto_b, x, nullf, x1, lnh_w, lnh_b,
                     hoinHi, hoinLo, gate_w, gate_b, scores);
  // gate mask
  hipLaunchKernelGGL(gate_mask_kernel, dim3(1), dim3(64), 0, stream, scores, maskb);
  // 5 HOA projections merged (3-pass exact) -> bf16 plane pair [T][5CC]
  hipLaunchKernelGGL(gemm_bf, dim3(60, 8, 1), blk, 0, stream, hoinHi, hoinLo, hoaT_h, hoaT_l,
                     nullf, (float*)nullptr, hoaPh, hoaPl,
                     TT, PW, CC, 0, 0, nullf, nullf, (float*)nullptr, 3);
  // HOA scores (both branches) + wave top-64 selection
  hipLaunchKernelGGL(score_gemm_kernel, dim3(8, 8, 2 * HH), blk, 0, stream,
                     hoaPh, hoaPl, hscores);
  hipLaunchKernelGGL(topk_select_kernel, dim3(2 * HH * TT / 4), blk, 0, stream,
                     hscores, idx1, idx2);
  // HOA core (bf16 planes, vectorized staging) -> hco hi plane
  hipLaunchKernelGGL(hoa_core_kernel, dim3(HH, TT), blk, 0, stream,
                     hoaPh, hoaPl, idx1, idx2, hcoHi);
  // ho GEMM (split-K 2, single-pass bf16)
  hipLaunchKernelGGL(gemm_bf, dim3(12, 8, 2), blk, 0, stream, hcoHi, nullu, hoT_h, nullu,
                     nullf, (float*)nullptr, nullu, nullu,
                     TT, CC, CC, 0, 0, nullf, nullf, gpart, 1);
  // fused: ho-combine (gate-mask, +x1 residual) -> x2, then LN2 -> h2 hi plane
  hipLaunchKernelGGL(combine_ln_kernel, dim3(TT), blk, 0, stream,
                     gpart, 2, nullf, x1, maskb, x2, ln2_w, ln2_b,
                     h2Hi, nullu, nullf, nullf, (float*)nullptr);
  // fc (single-pass bf16) + gelu -> fcb hi plane
  hipLaunchKernelGGL(gemm_bf, dim3(48, 8, 1), blk, 0, stream, h2Hi, nullu, fcT_h, nullu,
                     fc_b, (float*)nullptr, fcbHi, nullu,
                     TT, 4 * CC, CC, 1, 0, nullf, nullf, (float*)nullptr, 1);
  // pr (split-K 4, single-pass bf16) + residual -> out
  hipLaunchKernelGGL(gemm_bf, dim3(12, 8, 4), blk, 0, stream, fcbHi, nullu, prT_h, nullu,
                     nullf, (float*)nullptr, nullu, nullu,
                     TT, CC, 4 * CC, 0, 0, nullf, nullf, gpart, 1);
  hipLaunchKernelGGL(gemm_combine_kernel, dim3((NTCE + 255) / 256), blk, 0, stream,
                     gpart, 4, TT, CC, pr_b, out,
                     nullu, nullu, 0, x2, nullf);
}